// Round 8
// baseline (2792.984 us; speedup 1.0000x reference)
//
#include <hip/hip_runtime.h>
#include <hip/hip_bf16.h>
#include <math.h>

// Problem constants
#define N_   8
#define CIN_ 64
#define DIMS_ 64
#define NW_  8
#define T_   16
#define H_   64
#define W_   64
#define HW_  (H_ * W_)          // 4096
#define THW_ (T_ * HW_)         // 65536

typedef short bf16x8 __attribute__((ext_vector_type(8)));
typedef float f32x16 __attribute__((ext_vector_type(16)));

__device__ __forceinline__ unsigned short f2bf(float f) {
    union { float f; unsigned u; } a; a.f = f;
    unsigned r = a.u + 0x7fffu + ((a.u >> 16) & 1u);   // RNE
    return (unsigned short)(r >> 16);
}

// conv LDS geometry (halfword units)
#define CS8_ 8
#define HS8_ (66 * CS8_)        // 528
#define TS8_ (10 * HS8_)        // 5280
#define WB_  (28 * 64 * 8)      // 14336 hw = 28672 B (w buffer, single)
#define XB6_ (6 * TS8_)         // 31680 hw = 63360 B per x buffer (6 t-planes)
// dynamic LDS layout (hw): x0 | x1 | w | junk | bnred
#define XO0_   0
#define XO1_   XB6_                        // 31680
#define WOFF_  (2 * XB6_)                  // 63360
#define JUNK7_ (WOFF_ + WB_)               // 77696 (512 hw)
#define BNRED7_ (JUNK7_ + 512)             // 78208 (256 hw = 128 f32)
#define DLS7_BYTES_ ((BNRED7_ + 256) * 2)  // 156928 B

__host__ __device__ constexpr int OXc(int tap) {
    int tt = tap > 26 ? 26 : tap;   // tap 27 = zero-weight pad -> any safe addr
    return (tt / 9) * TS8_ + ((tt % 9) / 3) * HS8_ + ((tt % 3) - 1) * CS8_;
}

// ---------------------------------------------------------------------------
// 1) fused: temporal std (ddof=1) + x -> xb bf16 [n][c8][t][h][w][8cin]
//    + SE weight transpose (first 75 flat blocks) + zero sums/pooled (block 0)
__global__ __launch_bounds__(512) void stdxb_kernel(
    const float* __restrict__ x, float* __restrict__ std_x,
    unsigned short* __restrict__ xb, float* __restrict__ sums,
    unsigned* __restrict__ pooled,
    const float* __restrict__ w1, const float* __restrict__ w2,
    float* __restrict__ w1t, float* __restrict__ w2t)
{
    __shared__ unsigned short xsl[16 * 64 * 8];   // [t][w][c] 16 KB
    const int h = blockIdx.x, c8 = blockIdx.y, n = blockIdx.z;
    const int tid = threadIdx.x;
    const int bf = blockIdx.x + (blockIdx.y << 6) + ((int)blockIdx.z << 9);
    if (bf == 0) {
        if (tid < 128) sums[tid] = 0.f;
        else if (tid < 384) pooled[tid - 128] = 0u;
    }
    if (bf < 75) {
        int i = bf * 512 + tid;
        if (i < 25600) {
            int k = i / 1600, c = (i / 25) % 64, tap = i % 25;
            w1t[(c * 25 + tap) * 16 + k] = w1[i];
        } else if (i < 38400) {
            int j = i - 25600;
            int o = j / 400, c = (j / 25) % 16, tap = j % 25;
            w2t[(c * 25 + tap) * 32 + o] = w2[j];
        }
    }
    const int c = tid >> 6, w = tid & 63;
    const int cin = c8 * 8 + c;
    const float* px = x + (((size_t)(n * 64 + cin)) << 16) + (h << 6) + w;
    float s = 0.f, s2 = 0.f;
#pragma unroll
    for (int t = 0; t < T_; ++t) {
        float v = px[t * HW_];
        s += v;
        s2 += v * v;
        xsl[(t << 9) + (w << 3) + c] = f2bf(v);
    }
    float var = (s2 - s * s * (1.0f / 16.0f)) * (1.0f / 15.0f);
    std_x[(((size_t)(n * 64 + cin)) << 12) + (h << 6) + w] = sqrtf(fmaxf(var, 0.f));
    __syncthreads();
    const int4* src = (const int4*)xsl;
    int4* dst = (int4*)(xb + ((size_t)((n * 8 + c8) * 16) << 12) * 8);
#pragma unroll
    for (int k = 0; k < 2; ++k) {
        int j = tid + (k << 9);
        int t = j >> 6, ww = j & 63;
        dst[((t << 6) + h) * 64 + ww] = src[j];
    }
}

// ---------------------------------------------------------------------------
// 2) SE conv1: block 256 = 64 ij x 4 c-quarters; 8 k per thread; LDS reduce
__global__ __launch_bounds__(256) void se_conv1c(const float* __restrict__ std_x,
        const float* __restrict__ w1t, const float* __restrict__ b1, float* __restrict__ h1) {
    __shared__ float red[3][64][8];
    const int n = blockIdx.y, ks = blockIdx.z * 8;
    const int iq = threadIdx.x & 63, cq = threadIdx.x >> 6;
    const int ij = blockIdx.x * 64 + iq;
    float acc[8];
#pragma unroll
    for (int q = 0; q < 8; ++q) acc[q] = 0.f;
    if (ij < 3600) {
        int i = ij / 60, j = ij - i * 60;
        const float* xn = std_x + (size_t)n * CIN_ * HW_ + i * W_ + j;
        for (int c = cq * 16; c < cq * 16 + 16; ++c) {
            const float* xc = xn + c * HW_;
            float xv[25];
#pragma unroll
            for (int u = 0; u < 5; ++u)
#pragma unroll
                for (int v = 0; v < 5; ++v) xv[u * 5 + v] = xc[u * W_ + v];
            const float* wc = w1t + c * 400 + ks;
#pragma unroll
            for (int tap = 0; tap < 25; ++tap)
#pragma unroll
                for (int q = 0; q < 8; ++q)
                    acc[q] = fmaf(xv[tap], wc[tap * 16 + q], acc[q]);
        }
    }
    if (cq > 0) {
#pragma unroll
        for (int q = 0; q < 8; ++q) red[cq - 1][iq][q] = acc[q];
    }
    __syncthreads();
    if (cq == 0 && ij < 3600) {
#pragma unroll
        for (int q = 0; q < 8; ++q) {
            float a = acc[q] + red[0][iq][q] + red[1][iq][q] + red[2][iq][q] + b1[ks + q];
            h1[((size_t)(n * 16 + ks + q)) * 3600 + ij] = fmaxf(a, 0.f);
        }
    }
}

// ---------------------------------------------------------------------------
// 3) SE conv2 + fused max-pool
__global__ __launch_bounds__(256) void se_conv2c(const float* __restrict__ h1,
        const float* __restrict__ w2t, const float* __restrict__ b2,
        unsigned* __restrict__ pooled) {
    __shared__ float red[3][64][8];
    const int n = blockIdx.y, os = blockIdx.z * 8;
    const int iq = threadIdx.x & 63, cq = threadIdx.x >> 6;
    const int ij = blockIdx.x * 64 + iq;   // exact 49*64 = 3136
    const int i = ij / 56, j = ij - i * 56;
    float acc[8];
#pragma unroll
    for (int q = 0; q < 8; ++q) acc[q] = 0.f;
    const float* xn = h1 + (size_t)n * 16 * 3600 + i * 60 + j;
    for (int c = cq * 4; c < cq * 4 + 4; ++c) {
        const float* xc = xn + c * 3600;
        float xv[25];
#pragma unroll
        for (int u = 0; u < 5; ++u)
#pragma unroll
            for (int v = 0; v < 5; ++v) xv[u * 5 + v] = xc[u * 60 + v];
        const float* wc = w2t + c * 800 + os;
#pragma unroll
        for (int tap = 0; tap < 25; ++tap)
#pragma unroll
            for (int q = 0; q < 8; ++q)
                acc[q] = fmaf(xv[tap], wc[tap * 32 + q], acc[q]);
    }
    if (cq > 0) {
#pragma unroll
        for (int q = 0; q < 8; ++q) red[cq - 1][iq][q] = acc[q];
    }
    __syncthreads();
    if (cq == 0) {
#pragma unroll
        for (int q = 0; q < 8; ++q) {
            float a = fmaxf(acc[q] + red[0][iq][q] + red[1][iq][q] + red[2][iq][q] + b2[os + q], 0.f);
#pragma unroll
            for (int m = 1; m < 64; m <<= 1) a = fmaxf(a, __shfl_xor(a, m, 64));
            if (iq == 0) atomicMax(&pooled[n * 32 + os + q], __float_as_uint(a));
        }
    }
}

// ---------------------------------------------------------------------------
// 6) dyn weights + head fused; block 0 writes dyn_b; first 64 blocks zero tap-27
__global__ __launch_bounds__(256) void dyn_w_head(
    const float* __restrict__ weights, const float* __restrict__ pooled,
    const float* __restrict__ lin_w, const float* __restrict__ lin_b,
    const float* __restrict__ biases, const int* __restrict__ epochs,
    unsigned short* __restrict__ wtb2, float* __restrict__ dyn_b) {
    __shared__ float slog[8][8];
    __shared__ float sphi[64];
    const int tid = threadIdx.x;
    const int e = epochs[0];
    const float tau = (e < 10) ? (30.0f - 2.9f * (float)e) : 1.0f;
    if (tid < 64) {
        int b = tid >> 3, m = tid & 7;
        float acc = lin_b[m];
#pragma unroll
        for (int k = 0; k < 32; ++k) acc += pooled[b * 32 + k] * lin_w[m * 32 + k];
        slog[b][m] = acc / tau;
    }
    __syncthreads();
    if (tid < 8) {
        float mx = slog[tid][0];
#pragma unroll
        for (int m = 1; m < 8; ++m) mx = fmaxf(mx, slog[tid][m]);
        float ex[8], ssum = 0.f;
#pragma unroll
        for (int m = 0; m < 8; ++m) { ex[m] = expf(slog[tid][m] - mx); ssum += ex[m]; }
        float inv = 1.0f / ssum;
#pragma unroll
        for (int m = 0; m < 8; ++m) sphi[tid * 8 + m] = ex[m] * inv;
    }
    __syncthreads();
    if (blockIdx.x < 64) {
        int b = blockIdx.x >> 3, c8 = blockIdx.x & 7;
        unsigned* dst = (unsigned*)(wtb2 + (size_t)b * 114688 + (size_t)(c8 * 28 + 27) * 512);
        dst[tid] = 0u;
    }
    if (blockIdx.x == 0) {
#pragma unroll
        for (int idx = tid; idx < 512; idx += 256) {
            int b = idx >> 6, d = idx & 63;
            float a = 0.f;
#pragma unroll
            for (int m = 0; m < 8; ++m) a += sphi[b * 8 + m] * biases[m * DIMS_ + d];
            dyn_b[idx] = a;
        }
    }
    int f = blockIdx.x * 256 + tid;   // 0..110591 = co*1728 + cin*27 + tap
    if (f >= 110592) return;
    int tap = f % 27, cin = (f / 27) & 63, co = f / 1728;
    float wv[8];
#pragma unroll
    for (int m = 0; m < 8; ++m) wv[m] = weights[(size_t)m * 110592 + f];
    size_t dbase = (size_t)(cin >> 3) * 14336 + tap * 512 + co * 8 + (cin & 7);
#pragma unroll
    for (int b = 0; b < 8; ++b) {
        float acc = 0.f;
#pragma unroll
        for (int m = 0; m < 8; ++m) acc += sphi[b * 8 + m] * wv[m];
        wtb2[(size_t)b * 114688 + dbase] = f2bf(acc);
    }
}

// ---------------------------------------------------------------------------
// 7) conv3d v7: 1024 thr = 16 waves; block = 4t x 8h x 64w x 64co.
//    Wave = (t_loc, h-pair): 2x4 outer product (6 ds_reads -> 8 MFMAs, 0.75/MFMA).
//    x double-buffered via global_load_lds; w single LDS buffer via T14
//    reg-staged async split (load early, ds_write in post-compute window).
//    Counted vmcnt only (4 -> w regs ready, 2 -> x landed); never drain mid-loop.
extern __shared__ unsigned short dls[];

__global__ __launch_bounds__(1024) void conv3d_mfma7(
    const unsigned short* __restrict__ xb,     // [8][8][16][64][64][8]
    const unsigned short* __restrict__ wtb2,   // [8][8][28][64][8]
    const float* __restrict__ dynb,            // [8][64]
    float* __restrict__ y,                     // [8][64][16][64][64]
    float* __restrict__ sums)                  // [128]
{
    const int hb = blockIdx.x, tb = blockIdx.y, n = blockIdx.z;
    const int tid = threadIdx.x;
    const int lane = tid & 63, wid = tid >> 6;       // 16 waves
    const int lane31 = lane & 31, tau = lane >> 5;
    const int t_loc = wid >> 2, hp2 = wid & 3;       // wave -> (t-plane, h-pair)
    const int hbase = hb * 8, t2 = tb * 4;

    unsigned short* wbuf = dls + WOFF_;
    unsigned short* junk = dls + JUNK7_;
    float* bnred = (float*)(dls + BNRED7_);

    // zero both x buffers (halo rows / w-pads stay zero all chunks) + bnred
    for (int i = tid; i < (2 * XB6_) / 8; i += 1024)
        *(int4*)&dls[i * 8] = (int4){0, 0, 0, 0};
    if (tid < 128) bnred[tid] = 0.f;
    __syncthreads();

    const unsigned short* xnb = xb + (size_t)n * 4194304;     // [c8][t][h][w][8]
    const unsigned short* wnb = wtb2 + (size_t)n * 114688;    // [c8][28][64][8]

    // x staging: 60 rows (6t x 10h) of 1KB; uniform 4 gload_lds per wave
    auto STAGE_X = [&](int c8, int pb) {
        unsigned short* xbuf = dls + (pb ? XO1_ : XO0_);
#pragma unroll
        for (int k = 0; k < 4; ++k) {
            int u = wid + (k << 4);              // 0..63 (60 real + 4 junk)
            int tp = u / 10, hp = u - tp * 10;
            int gt = t2 + tp - 1, gh = hbase + hp - 1;
            bool ok = (u < 60) && ((unsigned)gt < 16u) && ((unsigned)gh < 64u);
            const unsigned short* gp = xnb +
                (ok ? (size_t)(((c8 * 16 + gt) * 64 + gh) * 512 + lane * 8)
                    : (size_t)(lane * 8));
            unsigned short* lp = ok ? (xbuf + tp * TS8_ + hp * HS8_ + CS8_) : junk;
            __builtin_amdgcn_global_load_lds(
                (const __attribute__((address_space(1))) void*)gp,
                (__attribute__((address_space(3))) void*)lp, 16, 0, 0);
        }
    };

    // w staging: regs (2 dwordx4/thread, uniform) then ds_write later
    int4 wr0, wr1;
    auto WLOAD = [&](int c8) {
        const int4* g = (const int4*)(wnb + (size_t)c8 * 14336);
        wr0 = g[tid];
        wr1 = g[tid < 768 ? 1024 + tid : 0];     // dummy keeps vmcnt uniform
    };
    auto WSTORE = [&]() {
        *(int4*)&wbuf[tid * 8] = wr0;
        if (tid < 768) *(int4*)&wbuf[(1024 + tid) * 8] = wr1;
    };

    f32x16 acc[2][4];
#pragma unroll
    for (int ci = 0; ci < 2; ++ci)
#pragma unroll
        for (int s = 0; s < 4; ++s)
            acc[ci][s] = (f32x16)(0.f);

    const int aBase = tau * 512 + lane31 * 8;
    int bsp[4];
#pragma unroll
    for (int s = 0; s < 4; ++s)
        bsp[s] = t_loc * TS8_ + (2 * hp2 + (s >> 1)) * HS8_
               + (1 + (s & 1) * 32 + lane31) * CS8_;

    // prologue: w(0) regs + x(0) staged; w(1) regs in flight
    WLOAD(0);
    STAGE_X(0, 0);
    asm volatile("s_waitcnt vmcnt(4)" ::: "memory");   // w(0) regs ready
    WSTORE();
    WLOAD(1);
    asm volatile("s_waitcnt vmcnt(2)" ::: "memory");   // x(0) landed
    asm volatile("s_waitcnt lgkmcnt(0)" ::: "memory"); // wstore visible
    __builtin_amdgcn_sched_barrier(0);
    __builtin_amdgcn_s_barrier();
    __builtin_amdgcn_sched_barrier(0);

    for (int c8 = 0; c8 < 8; ++c8) {
        if (c8 < 7) STAGE_X(c8 + 1, (c8 + 1) & 1);     // flies across compute

        const unsigned short* xsb = dls + ((c8 & 1) ? XO1_ : XO0_);
#pragma unroll
        for (int p = 0; p < 14; ++p) {
            const int xo = tau ? OXc(2 * p + 1) : OXc(2 * p);
            bf16x8 a0 = *(const bf16x8*)&wbuf[p * 1024 + aBase];
            bf16x8 a1 = *(const bf16x8*)&wbuf[p * 1024 + aBase + 256];
            bf16x8 b0 = *(const bf16x8*)&xsb[bsp[0] + xo];
            bf16x8 b1 = *(const bf16x8*)&xsb[bsp[1] + xo];
            bf16x8 b2 = *(const bf16x8*)&xsb[bsp[2] + xo];
            bf16x8 b3 = *(const bf16x8*)&xsb[bsp[3] + xo];
            acc[0][0] = __builtin_amdgcn_mfma_f32_32x32x16_bf16(a0, b0, acc[0][0], 0, 0, 0);
            acc[0][1] = __builtin_amdgcn_mfma_f32_32x32x16_bf16(a0, b1, acc[0][1], 0, 0, 0);
            acc[0][2] = __builtin_amdgcn_mfma_f32_32x32x16_bf16(a0, b2, acc[0][2], 0, 0, 0);
            acc[0][3] = __builtin_amdgcn_mfma_f32_32x32x16_bf16(a0, b3, acc[0][3], 0, 0, 0);
            acc[1][0] = __builtin_amdgcn_mfma_f32_32x32x16_bf16(a1, b0, acc[1][0], 0, 0, 0);
            acc[1][1] = __builtin_amdgcn_mfma_f32_32x32x16_bf16(a1, b1, acc[1][1], 0, 0, 0);
            acc[1][2] = __builtin_amdgcn_mfma_f32_32x32x16_bf16(a1, b2, acc[1][2], 0, 0, 0);
            acc[1][3] = __builtin_amdgcn_mfma_f32_32x32x16_bf16(a1, b3, acc[1][3], 0, 0, 0);
        }
        __builtin_amdgcn_sched_barrier(0);
        __builtin_amdgcn_s_barrier();                  // all waves done reading
        __builtin_amdgcn_sched_barrier(0);

        if (c8 < 7) {
            asm volatile("s_waitcnt vmcnt(4)" ::: "memory");   // w(c8+1) regs ready
            WSTORE();                                          // fill wbuf
            if (c8 < 6) {
                WLOAD(c8 + 2);
                asm volatile("s_waitcnt vmcnt(2)" ::: "memory");   // x(c8+1) landed
            } else {
                asm volatile("s_waitcnt vmcnt(0)" ::: "memory");
            }
            asm volatile("s_waitcnt lgkmcnt(0)" ::: "memory");     // wstore visible
            __builtin_amdgcn_sched_barrier(0);
            __builtin_amdgcn_s_barrier();
            __builtin_amdgcn_sched_barrier(0);
        }
    }

    // ---- epilogue: C/D col=lane31(w), row=(r&3)+8*(r>>2)+4*tau (+32*ci)
    const float* db = dynb + n * DIMS_;
    const int t_out = t2 + t_loc;
    const int h0 = hbase + 2 * hp2;
#pragma unroll
    for (int ci = 0; ci < 2; ++ci) {
#pragma unroll
        for (int r = 0; r < 16; ++r) {
            const int co = 32 * ci + (r & 3) + 8 * (r >> 2) + 4 * tau;
            const float bco = db[co];
            float ps = 0.f, ps2 = 0.f;
#pragma unroll
            for (int s = 0; s < 4; ++s) {
                float z = acc[ci][s][r] + bco;
                size_t yi = ((size_t)(n * 64 + co) << 16) + ((size_t)t_out << 12)
                          + ((size_t)(h0 + (s >> 1)) << 6) + (s & 1) * 32 + lane31;
                y[yi] = z;
                ps += z;
                ps2 += z * z;
            }
#pragma unroll
            for (int m = 1; m < 32; m <<= 1) {
                ps += __shfl_xor(ps, m, 64);
                ps2 += __shfl_xor(ps2, m, 64);
            }
            if (lane31 == 0) {
                atomicAdd(&bnred[co], ps);
                atomicAdd(&bnred[64 + co], ps2);
            }
        }
    }
    __syncthreads();
    if (tid < 128) atomicAdd(&sums[tid], bnred[tid]);
}

// ---------------------------------------------------------------------------
// 9) BN normalize + relu, float4, grid-stride, in place
__global__ void bn_norm4(const float* __restrict__ sums, const float* __restrict__ gamma,
                         const float* __restrict__ beta, float* __restrict__ y) {
    const float cnt = (float)(N_ * THW_);
    for (size_t idx = (size_t)blockIdx.x * 256 + threadIdx.x; idx < 8388608;
         idx += (size_t)4096 * 256) {
        int c = (int)((idx >> 14) & 63);
        float mean = sums[c] / cnt;
        float var = sums[64 + c] / cnt - mean * mean;
        float sc = gamma[c] * rsqrtf(var + 1e-5f);
        float sh = beta[c] - mean * sc;
        float4 v = ((float4*)y)[idx];
        v.x = fmaxf(fmaf(v.x, sc, sh), 0.f);
        v.y = fmaxf(fmaf(v.y, sc, sh), 0.f);
        v.z = fmaxf(fmaf(v.z, sc, sh), 0.f);
        v.w = fmaxf(fmaf(v.w, sc, sh), 0.f);
        ((float4*)y)[idx] = v;
    }
}

// ---------------------------------------------------------------------------
extern "C" void kernel_launch(void* const* d_in, const int* in_sizes, int n_in,
                              void* d_out, int out_size, void* d_ws, size_t ws_size,
                              hipStream_t stream) {
    const float* x       = (const float*)d_in[0];
    const float* weights = (const float*)d_in[1];
    const float* biases  = (const float*)d_in[2];
    const float* se_w1   = (const float*)d_in[3];
    const float* se_b1   = (const float*)d_in[4];
    const float* se_w2   = (const float*)d_in[5];
    const float* se_b2   = (const float*)d_in[6];
    const float* lin_w   = (const float*)d_in[7];
    const float* lin_b   = (const float*)d_in[8];
    const float* gamma   = (const float*)d_in[9];
    const float* beta    = (const float*)d_in[10];
    const int*   epochs  = (const int*)d_in[11];

    float* out = (float*)d_out;
    float* ws = (float*)d_ws;

    // workspace layout (float slots)
    const size_t STD_OFF  = 0;                        // 2,097,152
    const size_t H1_OFF   = STD_OFF + 2097152;        // 460,800
    const size_t SUMS_OFF = H1_OFF + 460800;          // 128
    const size_t POOL_OFF = SUMS_OFF + 128;           // 256
    const size_t PHI_OFF  = POOL_OFF + 256;           // 64 (unused)
    const size_t DYNB_OFF = PHI_OFF + 64;             // 512
    const size_t WTB_OFF  = DYNB_OFF + 512;           // 458,752 (bf16 x 917,504)
    const size_t W1T_OFF  = WTB_OFF + 458752;         // 25,600
    const size_t W2T_OFF  = W1T_OFF + 25600;          // 12,800
    const size_t XB_OFF   = W2T_OFF + 12800;          // 16,777,216 (bf16 x 33.5M)

    float* std_x  = ws + STD_OFF;
    float* h1     = ws + H1_OFF;
    float* sums   = ws + SUMS_OFF;
    float* pooled = ws + POOL_OFF;
    float* dynb   = ws + DYNB_OFF;
    unsigned short* wtb2 = (unsigned short*)(ws + WTB_OFF);
    float* w1t    = ws + W1T_OFF;
    float* w2t    = ws + W2T_OFF;
    unsigned short* xb = (unsigned short*)(ws + XB_OFF);

    // allow >64KB dynamic LDS for the conv kernel (idempotent, capture-safe)
    hipFuncSetAttribute((const void*)conv3d_mfma7,
                        hipFuncAttributeMaxDynamicSharedMemorySize, DLS7_BYTES_);

    stdxb_kernel<<<dim3(64, 8, 8), 512, 0, stream>>>(
        x, std_x, xb, sums, (unsigned*)pooled, se_w1, se_w2, w1t, w2t);

    se_conv1c<<<dim3(57, 8, 2), 256, 0, stream>>>(std_x, w1t, se_b1, h1);
    se_conv2c<<<dim3(49, 8, 4), 256, 0, stream>>>(h1, w2t, se_b2, (unsigned*)pooled);

    dyn_w_head<<<432, 256, 0, stream>>>(weights, pooled, lin_w, lin_b, biases, epochs,
                                        wtb2, dynb);

    conv3d_mfma7<<<dim3(8, 4, 8), 1024, DLS7_BYTES_, stream>>>(xb, wtb2, dynb, out, sums);

    bn_norm4<<<4096, 256, 0, stream>>>(sums, gamma, beta, out);
}

// Round 9
// 378.452 us; speedup vs baseline: 7.3800x; 7.3800x over previous
//
#include <hip/hip_runtime.h>
#include <hip/hip_bf16.h>
#include <math.h>

// Problem constants
#define N_   8
#define CIN_ 64
#define DIMS_ 64
#define NW_  8
#define T_   16
#define H_   64
#define W_   64
#define HW_  (H_ * W_)          // 4096
#define THW_ (T_ * HW_)         // 65536

typedef short bf16x8 __attribute__((ext_vector_type(8)));
typedef float f32x16 __attribute__((ext_vector_type(16)));

__device__ __forceinline__ unsigned short f2bf(float f) {
    union { float f; unsigned u; } a; a.f = f;
    unsigned r = a.u + 0x7fffu + ((a.u >> 16) & 1u);   // RNE
    return (unsigned short)(r >> 16);
}
__device__ __forceinline__ float bf2f(unsigned short u) {
    union { unsigned u; float f; } a; a.u = ((unsigned)u) << 16; return a.f;
}

// conv LDS geometry (halfword units): x [3t][10h][66w][8cin], w [28tap][64co][8cin]
#define CS8_ 8
#define HS8_ (66 * CS8_)        // 528
#define TS8_ (10 * HS8_)        // 5280
#define XSH_ (3 * TS8_)         // 15840 hw = 31680 B
#define WLH_ (28 * 64 * 8)      // 14336 hw = 28672 B

__host__ __device__ constexpr int OXc(int tap) {
    int tt = tap > 26 ? 26 : tap;   // tap 27 = zero-weight pad -> any safe addr
    return (tt / 9) * TS8_ + ((tt % 9) / 3) * HS8_ + ((tt % 3) - 1) * CS8_;
}

// ---------------------------------------------------------------------------
// 1) fused: temporal std (ddof=1) + x -> xb bf16 [n][c8][t][h][w][8cin]
//    + SE weight transpose (first 75 flat blocks) + zero sums/pooled (block 0)
__global__ __launch_bounds__(512) void stdxb_kernel(
    const float* __restrict__ x, float* __restrict__ std_x,
    unsigned short* __restrict__ xb, float* __restrict__ sums,
    unsigned* __restrict__ pooled,
    const float* __restrict__ w1, const float* __restrict__ w2,
    float* __restrict__ w1t, float* __restrict__ w2t)
{
    __shared__ unsigned short xsl[16 * 64 * 8];   // [t][w][c] 16 KB
    const int h = blockIdx.x, c8 = blockIdx.y, n = blockIdx.z;
    const int tid = threadIdx.x;
    const int bf = blockIdx.x + (blockIdx.y << 6) + ((int)blockIdx.z << 9);
    if (bf == 0) {
        if (tid < 128) sums[tid] = 0.f;
        else if (tid < 384) pooled[tid - 128] = 0u;
    }
    if (bf < 75) {
        int i = bf * 512 + tid;
        if (i < 25600) {
            int k = i / 1600, c = (i / 25) % 64, tap = i % 25;
            w1t[(c * 25 + tap) * 16 + k] = w1[i];
        } else if (i < 38400) {
            int j = i - 25600;
            int o = j / 400, c = (j / 25) % 16, tap = j % 25;
            w2t[(c * 25 + tap) * 32 + o] = w2[j];
        }
    }
    const int c = tid >> 6, w = tid & 63;
    const int cin = c8 * 8 + c;
    const float* px = x + (((size_t)(n * 64 + cin)) << 16) + (h << 6) + w;
    float s = 0.f, s2 = 0.f;
#pragma unroll
    for (int t = 0; t < T_; ++t) {
        float v = px[t * HW_];
        s += v;
        s2 += v * v;
        xsl[(t << 9) + (w << 3) + c] = f2bf(v);
    }
    float var = (s2 - s * s * (1.0f / 16.0f)) * (1.0f / 15.0f);
    std_x[(((size_t)(n * 64 + cin)) << 12) + (h << 6) + w] = sqrtf(fmaxf(var, 0.f));
    __syncthreads();
    const int4* src = (const int4*)xsl;
    int4* dst = (int4*)(xb + ((size_t)((n * 8 + c8) * 16) << 12) * 8);
#pragma unroll
    for (int k = 0; k < 2; ++k) {
        int j = tid + (k << 9);
        int t = j >> 6, ww = j & 63;
        dst[((t << 6) + h) * 64 + ww] = src[j];
    }
}

// ---------------------------------------------------------------------------
// 2) SE conv1: block 256 = 64 ij x 4 c-quarters; 4 k per thread (z-split 4)
__global__ __launch_bounds__(256) void se_conv1c(const float* __restrict__ std_x,
        const float* __restrict__ w1t, const float* __restrict__ b1, float* __restrict__ h1) {
    __shared__ float red[3][64][4];
    const int n = blockIdx.y, ks = blockIdx.z * 4;
    const int iq = threadIdx.x & 63, cq = threadIdx.x >> 6;
    const int ij = blockIdx.x * 64 + iq;
    float acc[4];
#pragma unroll
    for (int q = 0; q < 4; ++q) acc[q] = 0.f;
    if (ij < 3600) {
        int i = ij / 60, j = ij - i * 60;
        const float* xn = std_x + (size_t)n * CIN_ * HW_ + i * W_ + j;
        for (int c = cq * 16; c < cq * 16 + 16; ++c) {
            const float* xc = xn + c * HW_;
            float xv[25];
#pragma unroll
            for (int u = 0; u < 5; ++u)
#pragma unroll
                for (int v = 0; v < 5; ++v) xv[u * 5 + v] = xc[u * W_ + v];
            const float* wc = w1t + c * 400 + ks;
#pragma unroll
            for (int tap = 0; tap < 25; ++tap)
#pragma unroll
                for (int q = 0; q < 4; ++q)
                    acc[q] = fmaf(xv[tap], wc[tap * 16 + q], acc[q]);
        }
    }
    if (cq > 0) {
#pragma unroll
        for (int q = 0; q < 4; ++q) red[cq - 1][iq][q] = acc[q];
    }
    __syncthreads();
    if (cq == 0 && ij < 3600) {
#pragma unroll
        for (int q = 0; q < 4; ++q) {
            float a = acc[q] + red[0][iq][q] + red[1][iq][q] + red[2][iq][q] + b1[ks + q];
            h1[((size_t)(n * 16 + ks + q)) * 3600 + ij] = fmaxf(a, 0.f);
        }
    }
}

// ---------------------------------------------------------------------------
// 3) SE conv2 + fused max-pool; 4 o per thread (z-split 8)
__global__ __launch_bounds__(256) void se_conv2c(const float* __restrict__ h1,
        const float* __restrict__ w2t, const float* __restrict__ b2,
        unsigned* __restrict__ pooled) {
    __shared__ float red[3][64][4];
    const int n = blockIdx.y, os = blockIdx.z * 4;
    const int iq = threadIdx.x & 63, cq = threadIdx.x >> 6;
    const int ij = blockIdx.x * 64 + iq;   // exact 49*64 = 3136
    const int i = ij / 56, j = ij - i * 56;
    float acc[4];
#pragma unroll
    for (int q = 0; q < 4; ++q) acc[q] = 0.f;
    const float* xn = h1 + (size_t)n * 16 * 3600 + i * 60 + j;
    for (int c = cq * 4; c < cq * 4 + 4; ++c) {
        const float* xc = xn + c * 3600;
        float xv[25];
#pragma unroll
        for (int u = 0; u < 5; ++u)
#pragma unroll
            for (int v = 0; v < 5; ++v) xv[u * 5 + v] = xc[u * 60 + v];
        const float* wc = w2t + c * 800 + os;
#pragma unroll
        for (int tap = 0; tap < 25; ++tap)
#pragma unroll
            for (int q = 0; q < 4; ++q)
                acc[q] = fmaf(xv[tap], wc[tap * 32 + q], acc[q]);
    }
    if (cq > 0) {
#pragma unroll
        for (int q = 0; q < 4; ++q) red[cq - 1][iq][q] = acc[q];
    }
    __syncthreads();
    if (cq == 0) {
#pragma unroll
        for (int q = 0; q < 4; ++q) {
            float a = fmaxf(acc[q] + red[0][iq][q] + red[1][iq][q] + red[2][iq][q] + b2[os + q], 0.f);
#pragma unroll
            for (int m = 1; m < 64; m <<= 1) a = fmaxf(a, __shfl_xor(a, m, 64));
            if (iq == 0) atomicMax(&pooled[n * 32 + os + q], __float_as_uint(a));
        }
    }
}

// ---------------------------------------------------------------------------
// 6) dyn weights + head fused; block 0 writes dyn_b; first 64 blocks zero tap-27
__global__ __launch_bounds__(256) void dyn_w_head(
    const float* __restrict__ weights, const float* __restrict__ pooled,
    const float* __restrict__ lin_w, const float* __restrict__ lin_b,
    const float* __restrict__ biases, const int* __restrict__ epochs,
    unsigned short* __restrict__ wtb2, float* __restrict__ dyn_b) {
    __shared__ float slog[8][8];
    __shared__ float sphi[64];
    const int tid = threadIdx.x;
    const int e = epochs[0];
    const float tau = (e < 10) ? (30.0f - 2.9f * (float)e) : 1.0f;
    if (tid < 64) {
        int b = tid >> 3, m = tid & 7;
        float acc = lin_b[m];
#pragma unroll
        for (int k = 0; k < 32; ++k) acc += pooled[b * 32 + k] * lin_w[m * 32 + k];
        slog[b][m] = acc / tau;
    }
    __syncthreads();
    if (tid < 8) {
        float mx = slog[tid][0];
#pragma unroll
        for (int m = 1; m < 8; ++m) mx = fmaxf(mx, slog[tid][m]);
        float ex[8], ssum = 0.f;
#pragma unroll
        for (int m = 0; m < 8; ++m) { ex[m] = expf(slog[tid][m] - mx); ssum += ex[m]; }
        float inv = 1.0f / ssum;
#pragma unroll
        for (int m = 0; m < 8; ++m) sphi[tid * 8 + m] = ex[m] * inv;
    }
    __syncthreads();
    if (blockIdx.x < 64) {
        int b = blockIdx.x >> 3, c8 = blockIdx.x & 7;
        unsigned* dst = (unsigned*)(wtb2 + (size_t)b * 114688 + (size_t)(c8 * 28 + 27) * 512);
        dst[tid] = 0u;
    }
    if (blockIdx.x == 0) {
#pragma unroll
        for (int idx = tid; idx < 512; idx += 256) {
            int b = idx >> 6, d = idx & 63;
            float a = 0.f;
#pragma unroll
            for (int m = 0; m < 8; ++m) a += sphi[b * 8 + m] * biases[m * DIMS_ + d];
            dyn_b[idx] = a;
        }
    }
    int f = blockIdx.x * 256 + tid;   // 0..110591 = co*1728 + cin*27 + tap
    if (f >= 110592) return;
    int tap = f % 27, cin = (f / 27) & 63, co = f / 1728;
    float wv[8];
#pragma unroll
    for (int m = 0; m < 8; ++m) wv[m] = weights[(size_t)m * 110592 + f];
    size_t dbase = (size_t)(cin >> 3) * 14336 + tap * 512 + co * 8 + (cin & 7);
#pragma unroll
    for (int b = 0; b < 8; ++b) {
        float acc = 0.f;
#pragma unroll
        for (int m = 0; m < 8; ++m) acc += sphi[b * 8 + m] * wv[m];
        wtb2[(size_t)b * 114688 + dbase] = f2bf(acc);
    }
}

// ---------------------------------------------------------------------------
// 7) conv3d (r6 proven structure): 256 thr = 4 waves, wave = 2 h-rows -> 2x4
//    outer product; single-buffer LDS (60.9 KB, 2 blocks/CU); fused BN stats.
//    Epilogue writes bf16 y (ybf != nullptr) or fp32 y (fallback).
__global__ __launch_bounds__(256, 2) void conv3d_mfma5(
    const unsigned short* __restrict__ xb,     // [8][8][16][64][64][8]
    const unsigned short* __restrict__ wtb2,   // [8][8][28][64][8]
    const float* __restrict__ dynb,            // [8][64]
    float* __restrict__ y,                     // fp32 out (fallback path)
    unsigned short* __restrict__ ybf,          // bf16 y (fast path) or nullptr
    float* __restrict__ sums)                  // [128]
{
    __shared__ __align__(16) unsigned short xs[XSH_];
    __shared__ __align__(16) unsigned short wl[WLH_];
    __shared__ float bnred[128];

    const int hb = blockIdx.x, t = blockIdx.y, n = blockIdx.z;
    const int tid = threadIdx.x;
    const int lane = tid & 63, wid = tid >> 6;     // 4 waves
    const int lane31 = lane & 31, tau = lane >> 5;
    const int hbase = hb * 8;

    for (int i = tid; i < XSH_ / 8; i += 256)
        *(int4*)&xs[i * 8] = (int4){0, 0, 0, 0};
    if (tid < 128) bnred[tid] = 0.f;

    const unsigned short* xnb = xb + (size_t)n * 4194304;     // [c8][t][h][w][8]
    const unsigned short* wnb = wtb2 + (size_t)n * 114688;    // [c8][28][64][8]

    f32x16 acc[2][4];
#pragma unroll
    for (int ci = 0; ci < 2; ++ci)
#pragma unroll
        for (int s = 0; s < 4; ++s)
            acc[ci][s] = (f32x16)(0.f);

    const int aBase = tau * 512 + lane31 * 8;
    int bsp[4];
#pragma unroll
    for (int s = 0; s < 4; ++s)
        bsp[s] = (2 * wid + (s >> 1)) * HS8_ + (1 + (s & 1) * 32 + lane31) * CS8_;

    for (int c8 = 0; c8 < 8; ++c8) {
        __syncthreads();   // waves done reading previous chunk (also after zero-fill)
#pragma unroll
        for (int k = 0; k < 7; ++k) {
            int tp = wid + (k << 2);
            const unsigned short* gp = wnb + ((size_t)c8 * 14336 + tp * 512 + lane * 8);
            const unsigned short* lp = &wl[tp * 512];
            __builtin_amdgcn_global_load_lds(
                (const __attribute__((address_space(1))) void*)gp,
                (__attribute__((address_space(3))) void*)lp, 16, 0, 0);
        }
#pragma unroll
        for (int k = 0; k < 8; ++k) {
            int r = wid + (k << 2);
            if (r < 30) {
                int tp = (r >= 20) ? 2 : (r >= 10 ? 1 : 0);
                int hp = r - tp * 10;
                int gt = t + tp - 1, gh = hbase + hp - 1;
                if (((unsigned)gt < 16u) && ((unsigned)gh < 64u)) {
                    const unsigned short* gp = xnb + (size_t)(((c8 * 16 + gt) * 64 + gh) * 64 + lane) * 8;
                    const unsigned short* lp = &xs[tp * TS8_ + hp * HS8_ + CS8_];
                    __builtin_amdgcn_global_load_lds(
                        (const __attribute__((address_space(1))) void*)gp,
                        (__attribute__((address_space(3))) void*)lp, 16, 0, 0);
                }
            }
        }
        __syncthreads();   // vmcnt(0) drain -> chunk staged

#pragma unroll
        for (int p = 0; p < 14; ++p) {
            const int xo = tau ? OXc(2 * p + 1) : OXc(2 * p);
            bf16x8 a0 = *(const bf16x8*)&wl[p * 1024 + aBase];
            bf16x8 a1 = *(const bf16x8*)&wl[p * 1024 + aBase + 256];
            bf16x8 b0 = *(const bf16x8*)&xs[bsp[0] + xo];
            bf16x8 b1 = *(const bf16x8*)&xs[bsp[1] + xo];
            bf16x8 b2 = *(const bf16x8*)&xs[bsp[2] + xo];
            bf16x8 b3 = *(const bf16x8*)&xs[bsp[3] + xo];
            acc[0][0] = __builtin_amdgcn_mfma_f32_32x32x16_bf16(a0, b0, acc[0][0], 0, 0, 0);
            acc[0][1] = __builtin_amdgcn_mfma_f32_32x32x16_bf16(a0, b1, acc[0][1], 0, 0, 0);
            acc[0][2] = __builtin_amdgcn_mfma_f32_32x32x16_bf16(a0, b2, acc[0][2], 0, 0, 0);
            acc[0][3] = __builtin_amdgcn_mfma_f32_32x32x16_bf16(a0, b3, acc[0][3], 0, 0, 0);
            acc[1][0] = __builtin_amdgcn_mfma_f32_32x32x16_bf16(a1, b0, acc[1][0], 0, 0, 0);
            acc[1][1] = __builtin_amdgcn_mfma_f32_32x32x16_bf16(a1, b1, acc[1][1], 0, 0, 0);
            acc[1][2] = __builtin_amdgcn_mfma_f32_32x32x16_bf16(a1, b2, acc[1][2], 0, 0, 0);
            acc[1][3] = __builtin_amdgcn_mfma_f32_32x32x16_bf16(a1, b3, acc[1][3], 0, 0, 0);
        }
    }

    // ---- epilogue: C/D col=lane31(w), row=(r&3)+8*(r>>2)+4*tau (+32*ci)
    const float* db = dynb + n * DIMS_;
    const bool bf = (ybf != nullptr);
#pragma unroll
    for (int ci = 0; ci < 2; ++ci) {
#pragma unroll
        for (int r = 0; r < 16; ++r) {
            const int co = 32 * ci + (r & 3) + 8 * (r >> 2) + 4 * tau;
            const float bco = db[co];
            float ps = 0.f, ps2 = 0.f;
#pragma unroll
            for (int s = 0; s < 4; ++s) {
                float z = acc[ci][s][r] + bco;
                size_t yi = ((size_t)(n * 64 + co) << 16) + ((size_t)t << 12)
                          + ((size_t)(hbase + 2 * wid + (s >> 1)) << 6) + (s & 1) * 32 + lane31;
                if (bf) ybf[yi] = f2bf(z);
                else    y[yi] = z;
                ps += z;
                ps2 += z * z;
            }
#pragma unroll
            for (int m = 1; m < 32; m <<= 1) {
                ps += __shfl_xor(ps, m, 64);
                ps2 += __shfl_xor(ps2, m, 64);
            }
            if (lane31 == 0) {
                atomicAdd(&bnred[co], ps);
                atomicAdd(&bnred[64 + co], ps2);
            }
        }
    }
    __syncthreads();
    if (tid < 128) atomicAdd(&sums[tid], bnred[tid]);
}

// ---------------------------------------------------------------------------
// 9a) BN normalize + relu from bf16 y -> fp32 out (fast path)
__global__ void bn_norm_bf(const float* __restrict__ sums, const float* __restrict__ gamma,
                           const float* __restrict__ beta,
                           const unsigned short* __restrict__ ybf, float* __restrict__ out) {
    const float cnt = (float)(N_ * THW_);
    for (size_t i8 = (size_t)blockIdx.x * 256 + threadIdx.x; i8 < 4194304;
         i8 += (size_t)4096 * 256) {
        int c = (int)((i8 >> 13) & 63);
        float mean = sums[c] / cnt;
        float var = sums[64 + c] / cnt - mean * mean;
        float sc = gamma[c] * rsqrtf(var + 1e-5f);
        float sh = beta[c] - mean * sc;
        int4 raw = ((const int4*)ybf)[i8];
        const unsigned short* u = (const unsigned short*)&raw;
        float4 o0, o1;
        o0.x = fmaxf(fmaf(bf2f(u[0]), sc, sh), 0.f);
        o0.y = fmaxf(fmaf(bf2f(u[1]), sc, sh), 0.f);
        o0.z = fmaxf(fmaf(bf2f(u[2]), sc, sh), 0.f);
        o0.w = fmaxf(fmaf(bf2f(u[3]), sc, sh), 0.f);
        o1.x = fmaxf(fmaf(bf2f(u[4]), sc, sh), 0.f);
        o1.y = fmaxf(fmaf(bf2f(u[5]), sc, sh), 0.f);
        o1.z = fmaxf(fmaf(bf2f(u[6]), sc, sh), 0.f);
        o1.w = fmaxf(fmaf(bf2f(u[7]), sc, sh), 0.f);
        ((float4*)out)[i8 * 2]     = o0;
        ((float4*)out)[i8 * 2 + 1] = o1;
    }
}

// 9b) BN normalize + relu, fp32 in place (fallback)
__global__ void bn_norm4(const float* __restrict__ sums, const float* __restrict__ gamma,
                         const float* __restrict__ beta, float* __restrict__ y) {
    const float cnt = (float)(N_ * THW_);
    for (size_t idx = (size_t)blockIdx.x * 256 + threadIdx.x; idx < 8388608;
         idx += (size_t)4096 * 256) {
        int c = (int)((idx >> 14) & 63);
        float mean = sums[c] / cnt;
        float var = sums[64 + c] / cnt - mean * mean;
        float sc = gamma[c] * rsqrtf(var + 1e-5f);
        float sh = beta[c] - mean * sc;
        float4 v = ((float4*)y)[idx];
        v.x = fmaxf(fmaf(v.x, sc, sh), 0.f);
        v.y = fmaxf(fmaf(v.y, sc, sh), 0.f);
        v.z = fmaxf(fmaf(v.z, sc, sh), 0.f);
        v.w = fmaxf(fmaf(v.w, sc, sh), 0.f);
        ((float4*)y)[idx] = v;
    }
}

// ---------------------------------------------------------------------------
extern "C" void kernel_launch(void* const* d_in, const int* in_sizes, int n_in,
                              void* d_out, int out_size, void* d_ws, size_t ws_size,
                              hipStream_t stream) {
    const float* x       = (const float*)d_in[0];
    const float* weights = (const float*)d_in[1];
    const float* biases  = (const float*)d_in[2];
    const float* se_w1   = (const float*)d_in[3];
    const float* se_b1   = (const float*)d_in[4];
    const float* se_w2   = (const float*)d_in[5];
    const float* se_b2   = (const float*)d_in[6];
    const float* lin_w   = (const float*)d_in[7];
    const float* lin_b   = (const float*)d_in[8];
    const float* gamma   = (const float*)d_in[9];
    const float* beta    = (const float*)d_in[10];
    const int*   epochs  = (const int*)d_in[11];

    float* out = (float*)d_out;
    float* ws = (float*)d_ws;

    // workspace layout (float slots)
    const size_t STD_OFF  = 0;                        // 2,097,152
    const size_t H1_OFF   = STD_OFF + 2097152;        // 460,800
    const size_t SUMS_OFF = H1_OFF + 460800;          // 128
    const size_t POOL_OFF = SUMS_OFF + 128;           // 256
    const size_t PHI_OFF  = POOL_OFF + 256;           // 64 (unused)
    const size_t DYNB_OFF = PHI_OFF + 64;             // 512
    const size_t WTB_OFF  = DYNB_OFF + 512;           // 458,752 (bf16 x 917,504)
    const size_t W1T_OFF  = WTB_OFF + 458752;         // 25,600
    const size_t W2T_OFF  = W1T_OFF + 25600;          // 12,800
    const size_t XB_OFF   = W2T_OFF + 12800;          // 16,777,216 (bf16 x 33.5M)
    const size_t YBF_OFF  = XB_OFF + 16777216;        // 16,777,216 (bf16 x 33.5M)
    const size_t NEEDED   = (YBF_OFF + 16777216) * 4;

    float* std_x  = ws + STD_OFF;
    float* h1     = ws + H1_OFF;
    float* sums   = ws + SUMS_OFF;
    float* pooled = ws + POOL_OFF;
    float* dynb   = ws + DYNB_OFF;
    unsigned short* wtb2 = (unsigned short*)(ws + WTB_OFF);
    float* w1t    = ws + W1T_OFF;
    float* w2t    = ws + W2T_OFF;
    unsigned short* xb = (unsigned short*)(ws + XB_OFF);
    unsigned short* ybf = (unsigned short*)(ws + YBF_OFF);

    const bool bf_path = (ws_size >= NEEDED);

    stdxb_kernel<<<dim3(64, 8, 8), 512, 0, stream>>>(
        x, std_x, xb, sums, (unsigned*)pooled, se_w1, se_w2, w1t, w2t);

    se_conv1c<<<dim3(57, 8, 4), 256, 0, stream>>>(std_x, w1t, se_b1, h1);
    se_conv2c<<<dim3(49, 8, 8), 256, 0, stream>>>(h1, w2t, se_b2, (unsigned*)pooled);

    dyn_w_head<<<432, 256, 0, stream>>>(weights, pooled, lin_w, lin_b, biases, epochs,
                                        wtb2, dynb);

    conv3d_mfma5<<<dim3(8, 16, 8), 256, 0, stream>>>(
        xb, wtb2, dynb, out, bf_path ? ybf : nullptr, sums);

    if (bf_path)
        bn_norm_bf<<<4096, 256, 0, stream>>>(sums, gamma, beta, ybf, out);
    else
        bn_norm4<<<4096, 256, 0, stream>>>(sums, gamma, beta, out);
}

// Round 10
// 377.631 us; speedup vs baseline: 7.3961x; 1.0022x over previous
//
#include <hip/hip_runtime.h>
#include <hip/hip_bf16.h>
#include <math.h>

// Problem constants
#define N_   8
#define CIN_ 64
#define DIMS_ 64
#define NW_  8
#define T_   16
#define H_   64
#define W_   64
#define HW_  (H_ * W_)          // 4096
#define THW_ (T_ * HW_)         // 65536

typedef short bf16x8 __attribute__((ext_vector_type(8)));
typedef float f32x16 __attribute__((ext_vector_type(16)));

__device__ __forceinline__ unsigned short f2bf(float f) {
    union { float f; unsigned u; } a; a.f = f;
    unsigned r = a.u + 0x7fffu + ((a.u >> 16) & 1u);   // RNE
    return (unsigned short)(r >> 16);
}
__device__ __forceinline__ float bf2f(unsigned short u) {
    union { unsigned u; float f; } a; a.u = ((unsigned)u) << 16; return a.f;
}

// conv LDS geometry (halfword units): x [3t][10h][66w][8cin]
#define CS8_ 8
#define HS8_ (66 * CS8_)        // 528
#define TS8_ (10 * HS8_)        // 5280
#define XSH_ (3 * TS8_)         // 15840 hw = 31680 B

__host__ __device__ constexpr int OXc(int tap) {
    int tt = tap > 26 ? 26 : tap;   // tap 27 = zero-weight pad -> any safe addr
    return (tt / 9) * TS8_ + ((tt % 9) / 3) * HS8_ + ((tt % 3) - 1) * CS8_;
}

// ---------------------------------------------------------------------------
// 1) fused: temporal std (ddof=1) + x -> xb bf16 [n][c8][t][h][w][8cin]
//    + SE weight transpose (first 75 flat blocks) + zero sums/pooled (block 0)
__global__ __launch_bounds__(512) void stdxb_kernel(
    const float* __restrict__ x, float* __restrict__ std_x,
    unsigned short* __restrict__ xb, float* __restrict__ sums,
    unsigned* __restrict__ pooled,
    const float* __restrict__ w1, const float* __restrict__ w2,
    float* __restrict__ w1t, float* __restrict__ w2t)
{
    __shared__ unsigned short xsl[16 * 64 * 8];   // [t][w][c] 16 KB
    const int h = blockIdx.x, c8 = blockIdx.y, n = blockIdx.z;
    const int tid = threadIdx.x;
    const int bf = blockIdx.x + (blockIdx.y << 6) + ((int)blockIdx.z << 9);
    if (bf == 0) {
        if (tid < 128) sums[tid] = 0.f;
        else if (tid < 384) pooled[tid - 128] = 0u;
    }
    if (bf < 75) {
        int i = bf * 512 + tid;
        if (i < 25600) {
            int k = i / 1600, c = (i / 25) % 64, tap = i % 25;
            w1t[(c * 25 + tap) * 16 + k] = w1[i];
        } else if (i < 38400) {
            int j = i - 25600;
            int o = j / 400, c = (j / 25) % 16, tap = j % 25;
            w2t[(c * 25 + tap) * 32 + o] = w2[j];
        }
    }
    const int c = tid >> 6, w = tid & 63;
    const int cin = c8 * 8 + c;
    const float* px = x + (((size_t)(n * 64 + cin)) << 16) + (h << 6) + w;
    float s = 0.f, s2 = 0.f;
#pragma unroll
    for (int t = 0; t < T_; ++t) {
        float v = px[t * HW_];
        s += v;
        s2 += v * v;
        xsl[(t << 9) + (w << 3) + c] = f2bf(v);
    }
    float var = (s2 - s * s * (1.0f / 16.0f)) * (1.0f / 15.0f);
    std_x[(((size_t)(n * 64 + cin)) << 12) + (h << 6) + w] = sqrtf(fmaxf(var, 0.f));
    __syncthreads();
    const int4* src = (const int4*)xsl;
    int4* dst = (int4*)(xb + ((size_t)((n * 8 + c8) * 16) << 12) * 8);
#pragma unroll
    for (int k = 0; k < 2; ++k) {
        int j = tid + (k << 9);
        int t = j >> 6, ww = j & 63;
        dst[((t << 6) + h) * 64 + ww] = src[j];
    }
}

// ---------------------------------------------------------------------------
// 2) SE conv1: block 256 = 64 ij x 4 c-quarters; 8 k per thread; LDS reduce
__global__ __launch_bounds__(256) void se_conv1c(const float* __restrict__ std_x,
        const float* __restrict__ w1t, const float* __restrict__ b1, float* __restrict__ h1) {
    __shared__ float red[3][64][8];
    const int n = blockIdx.y, ks = blockIdx.z * 8;
    const int iq = threadIdx.x & 63, cq = threadIdx.x >> 6;
    const int ij = blockIdx.x * 64 + iq;
    float acc[8];
#pragma unroll
    for (int q = 0; q < 8; ++q) acc[q] = 0.f;
    if (ij < 3600) {
        int i = ij / 60, j = ij - i * 60;
        const float* xn = std_x + (size_t)n * CIN_ * HW_ + i * W_ + j;
        for (int c = cq * 16; c < cq * 16 + 16; ++c) {
            const float* xc = xn + c * HW_;
            float xv[25];
#pragma unroll
            for (int u = 0; u < 5; ++u)
#pragma unroll
                for (int v = 0; v < 5; ++v) xv[u * 5 + v] = xc[u * W_ + v];
            const float* wc = w1t + c * 400 + ks;
#pragma unroll
            for (int tap = 0; tap < 25; ++tap)
#pragma unroll
                for (int q = 0; q < 8; ++q)
                    acc[q] = fmaf(xv[tap], wc[tap * 16 + q], acc[q]);
        }
    }
    if (cq > 0) {
#pragma unroll
        for (int q = 0; q < 8; ++q) red[cq - 1][iq][q] = acc[q];
    }
    __syncthreads();
    if (cq == 0 && ij < 3600) {
#pragma unroll
        for (int q = 0; q < 8; ++q) {
            float a = acc[q] + red[0][iq][q] + red[1][iq][q] + red[2][iq][q] + b1[ks + q];
            h1[((size_t)(n * 16 + ks + q)) * 3600 + ij] = fmaxf(a, 0.f);
        }
    }
}

// ---------------------------------------------------------------------------
// 3) SE conv2 + fused max-pool
__global__ __launch_bounds__(256) void se_conv2c(const float* __restrict__ h1,
        const float* __restrict__ w2t, const float* __restrict__ b2,
        unsigned* __restrict__ pooled) {
    __shared__ float red[3][64][8];
    const int n = blockIdx.y, os = blockIdx.z * 8;
    const int iq = threadIdx.x & 63, cq = threadIdx.x >> 6;
    const int ij = blockIdx.x * 64 + iq;   // exact 49*64 = 3136
    const int i = ij / 56, j = ij - i * 56;
    float acc[8];
#pragma unroll
    for (int q = 0; q < 8; ++q) acc[q] = 0.f;
    const float* xn = h1 + (size_t)n * 16 * 3600 + i * 60 + j;
    for (int c = cq * 4; c < cq * 4 + 4; ++c) {
        const float* xc = xn + c * 3600;
        float xv[25];
#pragma unroll
        for (int u = 0; u < 5; ++u)
#pragma unroll
            for (int v = 0; v < 5; ++v) xv[u * 5 + v] = xc[u * 60 + v];
        const float* wc = w2t + c * 800 + os;
#pragma unroll
        for (int tap = 0; tap < 25; ++tap)
#pragma unroll
            for (int q = 0; q < 8; ++q)
                acc[q] = fmaf(xv[tap], wc[tap * 32 + q], acc[q]);
    }
    if (cq > 0) {
#pragma unroll
        for (int q = 0; q < 8; ++q) red[cq - 1][iq][q] = acc[q];
    }
    __syncthreads();
    if (cq == 0) {
#pragma unroll
        for (int q = 0; q < 8; ++q) {
            float a = fmaxf(acc[q] + red[0][iq][q] + red[1][iq][q] + red[2][iq][q] + b2[os + q], 0.f);
#pragma unroll
            for (int m = 1; m < 64; m <<= 1) a = fmaxf(a, __shfl_xor(a, m, 64));
            if (iq == 0) atomicMax(&pooled[n * 32 + os + q], __float_as_uint(a));
        }
    }
}

// ---------------------------------------------------------------------------
// 6) dyn weights + head fused; block 0 writes dyn_b; first 64 blocks zero tap-27
__global__ __launch_bounds__(256) void dyn_w_head(
    const float* __restrict__ weights, const float* __restrict__ pooled,
    const float* __restrict__ lin_w, const float* __restrict__ lin_b,
    const float* __restrict__ biases, const int* __restrict__ epochs,
    unsigned short* __restrict__ wtb2, float* __restrict__ dyn_b) {
    __shared__ float slog[8][8];
    __shared__ float sphi[64];
    const int tid = threadIdx.x;
    const int e = epochs[0];
    const float tau = (e < 10) ? (30.0f - 2.9f * (float)e) : 1.0f;
    if (tid < 64) {
        int b = tid >> 3, m = tid & 7;
        float acc = lin_b[m];
#pragma unroll
        for (int k = 0; k < 32; ++k) acc += pooled[b * 32 + k] * lin_w[m * 32 + k];
        slog[b][m] = acc / tau;
    }
    __syncthreads();
    if (tid < 8) {
        float mx = slog[tid][0];
#pragma unroll
        for (int m = 1; m < 8; ++m) mx = fmaxf(mx, slog[tid][m]);
        float ex[8], ssum = 0.f;
#pragma unroll
        for (int m = 0; m < 8; ++m) { ex[m] = expf(slog[tid][m] - mx); ssum += ex[m]; }
        float inv = 1.0f / ssum;
#pragma unroll
        for (int m = 0; m < 8; ++m) sphi[tid * 8 + m] = ex[m] * inv;
    }
    __syncthreads();
    if (blockIdx.x < 64) {
        int b = blockIdx.x >> 3, c8 = blockIdx.x & 7;
        unsigned* dst = (unsigned*)(wtb2 + (size_t)b * 114688 + (size_t)(c8 * 28 + 27) * 512);
        dst[tid] = 0u;
    }
    if (blockIdx.x == 0) {
#pragma unroll
        for (int idx = tid; idx < 512; idx += 256) {
            int b = idx >> 6, d = idx & 63;
            float a = 0.f;
#pragma unroll
            for (int m = 0; m < 8; ++m) a += sphi[b * 8 + m] * biases[m * DIMS_ + d];
            dyn_b[idx] = a;
        }
    }
    int f = blockIdx.x * 256 + tid;   // 0..110591 = co*1728 + cin*27 + tap
    if (f >= 110592) return;
    int tap = f % 27, cin = (f / 27) & 63, co = f / 1728;
    float wv[8];
#pragma unroll
    for (int m = 0; m < 8; ++m) wv[m] = weights[(size_t)m * 110592 + f];
    size_t dbase = (size_t)(cin >> 3) * 14336 + tap * 512 + co * 8 + (cin & 7);
#pragma unroll
    for (int b = 0; b < 8; ++b) {
        float acc = 0.f;
#pragma unroll
        for (int m = 0; m < 8; ++m) acc += sphi[b * 8 + m] * wv[m];
        wtb2[(size_t)b * 114688 + dbase] = f2bf(acc);
    }
}

// ---------------------------------------------------------------------------
// 7) conv3d v8: 256 thr = 4 waves, wave = 2 h-rows, 2x4 outer product.
//    A-operands (weights) loaded per-wave DIRECTLY FROM GLOBAL (L2-resident,
//    VMEM pipe) -- no w LDS buffer, no A ds_reads. LDS stages only x (31.7 KB,
//    B-reads 0.5/MFMA on LDS pipe). Fused BN stats; bf16 or fp32 y epilogue.
__global__ __launch_bounds__(256, 2) void conv3d_mfma8(
    const unsigned short* __restrict__ xb,     // [8][8][16][64][64][8]
    const unsigned short* __restrict__ wtb2,   // [8][8][28][64][8]
    const float* __restrict__ dynb,            // [8][64]
    float* __restrict__ y,                     // fp32 out (fallback path)
    unsigned short* __restrict__ ybf,          // bf16 y (fast path) or nullptr
    float* __restrict__ sums)                  // [128]
{
    __shared__ __align__(16) unsigned short xs[XSH_];
    __shared__ float bnred[128];

    const int hb = blockIdx.x, t = blockIdx.y, n = blockIdx.z;
    const int tid = threadIdx.x;
    const int lane = tid & 63, wid = tid >> 6;     // 4 waves
    const int lane31 = lane & 31, tau = lane >> 5;
    const int hbase = hb * 8;

    for (int i = tid; i < XSH_ / 8; i += 256)
        *(int4*)&xs[i * 8] = (int4){0, 0, 0, 0};
    if (tid < 128) bnred[tid] = 0.f;

    const unsigned short* xnb = xb + (size_t)n * 4194304;     // [c8][t][h][w][8]
    const unsigned short* wnb = wtb2 + (size_t)n * 114688;    // [c8][28][64][8]

    f32x16 acc[2][4];
#pragma unroll
    for (int ci = 0; ci < 2; ++ci)
#pragma unroll
        for (int s = 0; s < 4; ++s)
            acc[ci][s] = (f32x16)(0.f);

    // per-lane A base (halfwords within one chunk's [28][64][8] slab):
    // tap = 2p + tau, co = lane31 (+32 for a1), 8 cin contiguous
    const int aBase = tau * 512 + lane31 * 8;
    int bsp[4];
#pragma unroll
    for (int s = 0; s < 4; ++s)
        bsp[s] = (2 * wid + (s >> 1)) * HS8_ + (1 + (s & 1) * 32 + lane31) * CS8_;

    for (int c8 = 0; c8 < 8; ++c8) {
        __syncthreads();   // waves done reading previous chunk (also after zero-fill)
        // ---- stage x: rows wid+4k, k=0..7 (30 rows used)
#pragma unroll
        for (int k = 0; k < 8; ++k) {
            int r = wid + (k << 2);
            if (r < 30) {
                int tp = (r >= 20) ? 2 : (r >= 10 ? 1 : 0);
                int hp = r - tp * 10;
                int gt = t + tp - 1, gh = hbase + hp - 1;
                if (((unsigned)gt < 16u) && ((unsigned)gh < 64u)) {
                    const unsigned short* gp = xnb + (size_t)(((c8 * 16 + gt) * 64 + gh) * 64 + lane) * 8;
                    const unsigned short* lp = &xs[tp * TS8_ + hp * HS8_ + CS8_];
                    __builtin_amdgcn_global_load_lds(
                        (const __attribute__((address_space(1))) void*)gp,
                        (__attribute__((address_space(3))) void*)lp, 16, 0, 0);
                }
            }
        }
        __syncthreads();   // vmcnt(0) drain -> chunk staged

        const unsigned short* wA = wnb + (size_t)c8 * 14336;
#pragma unroll
        for (int p = 0; p < 14; ++p) {
            const int xo = tau ? OXc(2 * p + 1) : OXc(2 * p);
            bf16x8 a0 = *(const bf16x8*)(wA + p * 1024 + aBase);          // global (L2)
            bf16x8 a1 = *(const bf16x8*)(wA + p * 1024 + aBase + 256);    // global (L2)
            bf16x8 b0 = *(const bf16x8*)&xs[bsp[0] + xo];
            bf16x8 b1 = *(const bf16x8*)&xs[bsp[1] + xo];
            bf16x8 b2 = *(const bf16x8*)&xs[bsp[2] + xo];
            bf16x8 b3 = *(const bf16x8*)&xs[bsp[3] + xo];
            acc[0][0] = __builtin_amdgcn_mfma_f32_32x32x16_bf16(a0, b0, acc[0][0], 0, 0, 0);
            acc[0][1] = __builtin_amdgcn_mfma_f32_32x32x16_bf16(a0, b1, acc[0][1], 0, 0, 0);
            acc[0][2] = __builtin_amdgcn_mfma_f32_32x32x16_bf16(a0, b2, acc[0][2], 0, 0, 0);
            acc[0][3] = __builtin_amdgcn_mfma_f32_32x32x16_bf16(a0, b3, acc[0][3], 0, 0, 0);
            acc[1][0] = __builtin_amdgcn_mfma_f32_32x32x16_bf16(a1, b0, acc[1][0], 0, 0, 0);
            acc[1][1] = __builtin_amdgcn_mfma_f32_32x32x16_bf16(a1, b1, acc[1][1], 0, 0, 0);
            acc[1][2] = __builtin_amdgcn_mfma_f32_32x32x16_bf16(a1, b2, acc[1][2], 0, 0, 0);
            acc[1][3] = __builtin_amdgcn_mfma_f32_32x32x16_bf16(a1, b3, acc[1][3], 0, 0, 0);
        }
    }

    // ---- epilogue: C/D col=lane31(w), row=(r&3)+8*(r>>2)+4*tau (+32*ci)
    const float* db = dynb + n * DIMS_;
    const bool bf = (ybf != nullptr);
#pragma unroll
    for (int ci = 0; ci < 2; ++ci) {
#pragma unroll
        for (int r = 0; r < 16; ++r) {
            const int co = 32 * ci + (r & 3) + 8 * (r >> 2) + 4 * tau;
            const float bco = db[co];
            float ps = 0.f, ps2 = 0.f;
#pragma unroll
            for (int s = 0; s < 4; ++s) {
                float z = acc[ci][s][r] + bco;
                size_t yi = ((size_t)(n * 64 + co) << 16) + ((size_t)t << 12)
                          + ((size_t)(hbase + 2 * wid + (s >> 1)) << 6) + (s & 1) * 32 + lane31;
                if (bf) ybf[yi] = f2bf(z);
                else    y[yi] = z;
                ps += z;
                ps2 += z * z;
            }
#pragma unroll
            for (int m = 1; m < 32; m <<= 1) {
                ps += __shfl_xor(ps, m, 64);
                ps2 += __shfl_xor(ps2, m, 64);
            }
            if (lane31 == 0) {
                atomicAdd(&bnred[co], ps);
                atomicAdd(&bnred[64 + co], ps2);
            }
        }
    }
    __syncthreads();
    if (tid < 128) atomicAdd(&sums[tid], bnred[tid]);
}

// ---------------------------------------------------------------------------
// 9a) BN normalize + relu from bf16 y -> fp32 out (fast path)
__global__ void bn_norm_bf(const float* __restrict__ sums, const float* __restrict__ gamma,
                           const float* __restrict__ beta,
                           const unsigned short* __restrict__ ybf, float* __restrict__ out) {
    const float cnt = (float)(N_ * THW_);
    for (size_t i8 = (size_t)blockIdx.x * 256 + threadIdx.x; i8 < 4194304;
         i8 += (size_t)4096 * 256) {
        int c = (int)((i8 >> 13) & 63);
        float mean = sums[c] / cnt;
        float var = sums[64 + c] / cnt - mean * mean;
        float sc = gamma[c] * rsqrtf(var + 1e-5f);
        float sh = beta[c] - mean * sc;
        int4 raw = ((const int4*)ybf)[i8];
        const unsigned short* u = (const unsigned short*)&raw;
        float4 o0, o1;
        o0.x = fmaxf(fmaf(bf2f(u[0]), sc, sh), 0.f);
        o0.y = fmaxf(fmaf(bf2f(u[1]), sc, sh), 0.f);
        o0.z = fmaxf(fmaf(bf2f(u[2]), sc, sh), 0.f);
        o0.w = fmaxf(fmaf(bf2f(u[3]), sc, sh), 0.f);
        o1.x = fmaxf(fmaf(bf2f(u[4]), sc, sh), 0.f);
        o1.y = fmaxf(fmaf(bf2f(u[5]), sc, sh), 0.f);
        o1.z = fmaxf(fmaf(bf2f(u[6]), sc, sh), 0.f);
        o1.w = fmaxf(fmaf(bf2f(u[7]), sc, sh), 0.f);
        ((float4*)out)[i8 * 2]     = o0;
        ((float4*)out)[i8 * 2 + 1] = o1;
    }
}

// 9b) BN normalize + relu, fp32 in place (fallback)
__global__ void bn_norm4(const float* __restrict__ sums, const float* __restrict__ gamma,
                         const float* __restrict__ beta, float* __restrict__ y) {
    const float cnt = (float)(N_ * THW_);
    for (size_t idx = (size_t)blockIdx.x * 256 + threadIdx.x; idx < 8388608;
         idx += (size_t)4096 * 256) {
        int c = (int)((idx >> 14) & 63);
        float mean = sums[c] / cnt;
        float var = sums[64 + c] / cnt - mean * mean;
        float sc = gamma[c] * rsqrtf(var + 1e-5f);
        float sh = beta[c] - mean * sc;
        float4 v = ((float4*)y)[idx];
        v.x = fmaxf(fmaf(v.x, sc, sh), 0.f);
        v.y = fmaxf(fmaf(v.y, sc, sh), 0.f);
        v.z = fmaxf(fmaf(v.z, sc, sh), 0.f);
        v.w = fmaxf(fmaf(v.w, sc, sh), 0.f);
        ((float4*)y)[idx] = v;
    }
}

// ---------------------------------------------------------------------------
extern "C" void kernel_launch(void* const* d_in, const int* in_sizes, int n_in,
                              void* d_out, int out_size, void* d_ws, size_t ws_size,
                              hipStream_t stream) {
    const float* x       = (const float*)d_in[0];
    const float* weights = (const float*)d_in[1];
    const float* biases  = (const float*)d_in[2];
    const float* se_w1   = (const float*)d_in[3];
    const float* se_b1   = (const float*)d_in[4];
    const float* se_w2   = (const float*)d_in[5];
    const float* se_b2   = (const float*)d_in[6];
    const float* lin_w   = (const float*)d_in[7];
    const float* lin_b   = (const float*)d_in[8];
    const float* gamma   = (const float*)d_in[9];
    const float* beta    = (const float*)d_in[10];
    const int*   epochs  = (const int*)d_in[11];

    float* out = (float*)d_out;
    float* ws = (float*)d_ws;

    // workspace layout (float slots)
    const size_t STD_OFF  = 0;                        // 2,097,152
    const size_t H1_OFF   = STD_OFF + 2097152;        // 460,800
    const size_t SUMS_OFF = H1_OFF + 460800;          // 128
    const size_t POOL_OFF = SUMS_OFF + 128;           // 256
    const size_t PHI_OFF  = POOL_OFF + 256;           // 64 (unused)
    const size_t DYNB_OFF = PHI_OFF + 64;             // 512
    const size_t WTB_OFF  = DYNB_OFF + 512;           // 458,752 (bf16 x 917,504)
    const size_t W1T_OFF  = WTB_OFF + 458752;         // 25,600
    const size_t W2T_OFF  = W1T_OFF + 25600;          // 12,800
    const size_t XB_OFF   = W2T_OFF + 12800;          // 16,777,216 (bf16 x 33.5M)
    const size_t YBF_OFF  = XB_OFF + 16777216;        // 16,777,216 (bf16 x 33.5M)
    const size_t NEEDED   = (YBF_OFF + 16777216) * 4;

    float* std_x  = ws + STD_OFF;
    float* h1     = ws + H1_OFF;
    float* sums   = ws + SUMS_OFF;
    float* pooled = ws + POOL_OFF;
    float* dynb   = ws + DYNB_OFF;
    unsigned short* wtb2 = (unsigned short*)(ws + WTB_OFF);
    float* w1t    = ws + W1T_OFF;
    float* w2t    = ws + W2T_OFF;
    unsigned short* xb = (unsigned short*)(ws + XB_OFF);
    unsigned short* ybf = (unsigned short*)(ws + YBF_OFF);

    const bool bf_path = (ws_size >= NEEDED);

    stdxb_kernel<<<dim3(64, 8, 8), 512, 0, stream>>>(
        x, std_x, xb, sums, (unsigned*)pooled, se_w1, se_w2, w1t, w2t);

    se_conv1c<<<dim3(57, 8, 2), 256, 0, stream>>>(std_x, w1t, se_b1, h1);
    se_conv2c<<<dim3(49, 8, 4), 256, 0, stream>>>(h1, w2t, se_b2, (unsigned*)pooled);

    dyn_w_head<<<432, 256, 0, stream>>>(weights, pooled, lin_w, lin_b, biases, epochs,
                                        wtb2, dynb);

    conv3d_mfma8<<<dim3(8, 16, 8), 256, 0, stream>>>(
        xb, wtb2, dynb, out, bf_path ? ybf : nullptr, sums);

    if (bf_path)
        bn_norm_bf<<<4096, 256, 0, stream>>>(sums, gamma, beta, ybf, out);
    else
        bn_norm4<<<4096, 256, 0, stream>>>(sums, gamma, beta, out);
}

// Round 12
// 373.459 us; speedup vs baseline: 7.4787x; 1.0112x over previous
//
#include <hip/hip_runtime.h>
#include <hip/hip_bf16.h>
#include <math.h>

// Problem constants
#define N_   8
#define CIN_ 64
#define DIMS_ 64
#define NW_  8
#define T_   16
#define H_   64
#define W_   64
#define HW_  (H_ * W_)          // 4096
#define THW_ (T_ * HW_)         // 65536

typedef short bf16x8 __attribute__((ext_vector_type(8)));
typedef float f32x16 __attribute__((ext_vector_type(16)));
typedef int   i32x4v __attribute__((ext_vector_type(4)));
typedef float f32x4v __attribute__((ext_vector_type(4)));

__device__ __forceinline__ unsigned short f2bf(float f) {
    union { float f; unsigned u; } a; a.f = f;
    unsigned r = a.u + 0x7fffu + ((a.u >> 16) & 1u);   // RNE
    return (unsigned short)(r >> 16);
}
__device__ __forceinline__ float bf2f(unsigned short u) {
    union { unsigned u; float f; } a; a.u = ((unsigned)u) << 16; return a.f;
}

// conv LDS geometry (halfword units): x [3t][10h][66w][8cin], w [28tap][64co][8cin]
#define CS8_ 8
#define HS8_ (66 * CS8_)        // 528
#define TS8_ (10 * HS8_)        // 5280
#define XSH_ (3 * TS8_)         // 15840 hw = 31680 B
#define WLH_ (28 * 64 * 8)      // 14336 hw = 28672 B

__host__ __device__ constexpr int OXc(int tap) {
    int tt = tap > 26 ? 26 : tap;   // tap 27 = zero-weight pad -> any safe addr
    return (tt / 9) * TS8_ + ((tt % 9) / 3) * HS8_ + ((tt % 3) - 1) * CS8_;
}

// ---------------------------------------------------------------------------
// 1) fused: temporal std (ddof=1) + x -> xb bf16 [n][c8][t][h][w][8cin]
//    + SE weight transpose (first 75 flat blocks) + zero sums/pooled (block 0)
__global__ __launch_bounds__(512) void stdxb_kernel(
    const float* __restrict__ x, float* __restrict__ std_x,
    unsigned short* __restrict__ xb, float* __restrict__ sums,
    unsigned* __restrict__ pooled,
    const float* __restrict__ w1, const float* __restrict__ w2,
    float* __restrict__ w1t, float* __restrict__ w2t)
{
    __shared__ unsigned short xsl[16 * 64 * 8];   // [t][w][c] 16 KB
    const int h = blockIdx.x, c8 = blockIdx.y, n = blockIdx.z;
    const int tid = threadIdx.x;
    const int bf = blockIdx.x + (blockIdx.y << 6) + ((int)blockIdx.z << 9);
    if (bf == 0) {
        if (tid < 128) sums[tid] = 0.f;
        else if (tid < 384) pooled[tid - 128] = 0u;
    }
    if (bf < 75) {
        int i = bf * 512 + tid;
        if (i < 25600) {
            int k = i / 1600, c = (i / 25) % 64, tap = i % 25;
            w1t[(c * 25 + tap) * 16 + k] = w1[i];
        } else if (i < 38400) {
            int j = i - 25600;
            int o = j / 400, c = (j / 25) % 16, tap = j % 25;
            w2t[(c * 25 + tap) * 32 + o] = w2[j];
        }
    }
    const int c = tid >> 6, w = tid & 63;
    const int cin = c8 * 8 + c;
    const float* px = x + (((size_t)(n * 64 + cin)) << 16) + (h << 6) + w;
    float s = 0.f, s2 = 0.f;
#pragma unroll
    for (int t = 0; t < T_; ++t) {
        float v = px[t * HW_];
        s += v;
        s2 += v * v;
        xsl[(t << 9) + (w << 3) + c] = f2bf(v);
    }
    float var = (s2 - s * s * (1.0f / 16.0f)) * (1.0f / 15.0f);
    std_x[(((size_t)(n * 64 + cin)) << 12) + (h << 6) + w] = sqrtf(fmaxf(var, 0.f));
    __syncthreads();
    const int4* src = (const int4*)xsl;
    int4* dst = (int4*)(xb + ((size_t)((n * 8 + c8) * 16) << 12) * 8);
#pragma unroll
    for (int k = 0; k < 2; ++k) {
        int j = tid + (k << 9);
        int t = j >> 6, ww = j & 63;
        dst[((t << 6) + h) * 64 + ww] = src[j];
    }
}

// ---------------------------------------------------------------------------
// 2) SE conv1: block 256 = 64 ij x 4 c-quarters; 8 k per thread; LDS reduce
__global__ __launch_bounds__(256) void se_conv1c(const float* __restrict__ std_x,
        const float* __restrict__ w1t, const float* __restrict__ b1, float* __restrict__ h1) {
    __shared__ float red[3][64][8];
    const int n = blockIdx.y, ks = blockIdx.z * 8;
    const int iq = threadIdx.x & 63, cq = threadIdx.x >> 6;
    const int ij = blockIdx.x * 64 + iq;
    float acc[8];
#pragma unroll
    for (int q = 0; q < 8; ++q) acc[q] = 0.f;
    if (ij < 3600) {
        int i = ij / 60, j = ij - i * 60;
        const float* xn = std_x + (size_t)n * CIN_ * HW_ + i * W_ + j;
        for (int c = cq * 16; c < cq * 16 + 16; ++c) {
            const float* xc = xn + c * HW_;
            float xv[25];
#pragma unroll
            for (int u = 0; u < 5; ++u)
#pragma unroll
                for (int v = 0; v < 5; ++v) xv[u * 5 + v] = xc[u * W_ + v];
            const float* wc = w1t + c * 400 + ks;
#pragma unroll
            for (int tap = 0; tap < 25; ++tap)
#pragma unroll
                for (int q = 0; q < 8; ++q)
                    acc[q] = fmaf(xv[tap], wc[tap * 16 + q], acc[q]);
        }
    }
    if (cq > 0) {
#pragma unroll
        for (int q = 0; q < 8; ++q) red[cq - 1][iq][q] = acc[q];
    }
    __syncthreads();
    if (cq == 0 && ij < 3600) {
#pragma unroll
        for (int q = 0; q < 8; ++q) {
            float a = acc[q] + red[0][iq][q] + red[1][iq][q] + red[2][iq][q] + b1[ks + q];
            h1[((size_t)(n * 16 + ks + q)) * 3600 + ij] = fmaxf(a, 0.f);
        }
    }
}

// ---------------------------------------------------------------------------
// 3) SE conv2 + fused max-pool
__global__ __launch_bounds__(256) void se_conv2c(const float* __restrict__ h1,
        const float* __restrict__ w2t, const float* __restrict__ b2,
        unsigned* __restrict__ pooled) {
    __shared__ float red[3][64][8];
    const int n = blockIdx.y, os = blockIdx.z * 8;
    const int iq = threadIdx.x & 63, cq = threadIdx.x >> 6;
    const int ij = blockIdx.x * 64 + iq;   // exact 49*64 = 3136
    const int i = ij / 56, j = ij - i * 56;
    float acc[8];
#pragma unroll
    for (int q = 0; q < 8; ++q) acc[q] = 0.f;
    const float* xn = h1 + (size_t)n * 16 * 3600 + i * 60 + j;
    for (int c = cq * 4; c < cq * 4 + 4; ++c) {
        const float* xc = xn + c * 3600;
        float xv[25];
#pragma unroll
        for (int u = 0; u < 5; ++u)
#pragma unroll
            for (int v = 0; v < 5; ++v) xv[u * 5 + v] = xc[u * 60 + v];
        const float* wc = w2t + c * 800 + os;
#pragma unroll
        for (int tap = 0; tap < 25; ++tap)
#pragma unroll
            for (int q = 0; q < 8; ++q)
                acc[q] = fmaf(xv[tap], wc[tap * 32 + q], acc[q]);
    }
    if (cq > 0) {
#pragma unroll
        for (int q = 0; q < 8; ++q) red[cq - 1][iq][q] = acc[q];
    }
    __syncthreads();
    if (cq == 0) {
#pragma unroll
        for (int q = 0; q < 8; ++q) {
            float a = fmaxf(acc[q] + red[0][iq][q] + red[1][iq][q] + red[2][iq][q] + b2[os + q], 0.f);
#pragma unroll
            for (int m = 1; m < 64; m <<= 1) a = fmaxf(a, __shfl_xor(a, m, 64));
            if (iq == 0) atomicMax(&pooled[n * 32 + os + q], __float_as_uint(a));
        }
    }
}

// ---------------------------------------------------------------------------
// 6) dyn weights + head fused; block 0 writes dyn_b; first 64 blocks zero tap-27
__global__ __launch_bounds__(256) void dyn_w_head(
    const float* __restrict__ weights, const float* __restrict__ pooled,
    const float* __restrict__ lin_w, const float* __restrict__ lin_b,
    const float* __restrict__ biases, const int* __restrict__ epochs,
    unsigned short* __restrict__ wtb2, float* __restrict__ dyn_b) {
    __shared__ float slog[8][8];
    __shared__ float sphi[64];
    const int tid = threadIdx.x;
    const int e = epochs[0];
    const float tau = (e < 10) ? (30.0f - 2.9f * (float)e) : 1.0f;
    if (tid < 64) {
        int b = tid >> 3, m = tid & 7;
        float acc = lin_b[m];
#pragma unroll
        for (int k = 0; k < 32; ++k) acc += pooled[b * 32 + k] * lin_w[m * 32 + k];
        slog[b][m] = acc / tau;
    }
    __syncthreads();
    if (tid < 8) {
        float mx = slog[tid][0];
#pragma unroll
        for (int m = 1; m < 8; ++m) mx = fmaxf(mx, slog[tid][m]);
        float ex[8], ssum = 0.f;
#pragma unroll
        for (int m = 0; m < 8; ++m) { ex[m] = expf(slog[tid][m] - mx); ssum += ex[m]; }
        float inv = 1.0f / ssum;
#pragma unroll
        for (int m = 0; m < 8; ++m) sphi[tid * 8 + m] = ex[m] * inv;
    }
    __syncthreads();
    if (blockIdx.x < 64) {
        int b = blockIdx.x >> 3, c8 = blockIdx.x & 7;
        unsigned* dst = (unsigned*)(wtb2 + (size_t)b * 114688 + (size_t)(c8 * 28 + 27) * 512);
        dst[tid] = 0u;
    }
    if (blockIdx.x == 0) {
#pragma unroll
        for (int idx = tid; idx < 512; idx += 256) {
            int b = idx >> 6, d = idx & 63;
            float a = 0.f;
#pragma unroll
            for (int m = 0; m < 8; ++m) a += sphi[b * 8 + m] * biases[m * DIMS_ + d];
            dyn_b[idx] = a;
        }
    }
    int f = blockIdx.x * 256 + tid;   // 0..110591 = co*1728 + cin*27 + tap
    if (f >= 110592) return;
    int tap = f % 27, cin = (f / 27) & 63, co = f / 1728;
    float wv[8];
#pragma unroll
    for (int m = 0; m < 8; ++m) wv[m] = weights[(size_t)m * 110592 + f];
    size_t dbase = (size_t)(cin >> 3) * 14336 + tap * 512 + co * 8 + (cin & 7);
#pragma unroll
    for (int b = 0; b < 8; ++b) {
        float acc = 0.f;
#pragma unroll
        for (int m = 0; m < 8; ++m) acc += sphi[b * 8 + m] * wv[m];
        wtb2[(size_t)b * 114688 + dbase] = f2bf(acc);
    }
}

// ---------------------------------------------------------------------------
// 7) conv3d (proven r6 structure + XCD-aware mapping): 1-D grid 1024;
//    flat&7 = n  =>  each XCD owns one sample's tiles (w slab + xb slab +
//    halo re-reads become XCD-local L2 traffic). 256 thr = 4 waves, wave =
//    2 h-rows, 2x4 outer product; single-buffer LDS; fused BN stats;
//    bf16 (fast) or fp32 (fallback) y epilogue.
__global__ __launch_bounds__(256, 2) void conv3d_mfma5(
    const unsigned short* __restrict__ xb,     // [8][8][16][64][64][8]
    const unsigned short* __restrict__ wtb2,   // [8][8][28][64][8]
    const float* __restrict__ dynb,            // [8][64]
    float* __restrict__ y,                     // fp32 out (fallback path)
    unsigned short* __restrict__ ybf,          // bf16 y (fast path) or nullptr
    float* __restrict__ sums)                  // [128]
{
    __shared__ __align__(16) unsigned short xs[XSH_];
    __shared__ __align__(16) unsigned short wl[WLH_];
    __shared__ float bnred[128];

    const int flat = blockIdx.x;
    const int n = flat & 7;                 // XCD = dispatch%8 -> n-per-XCD
    const int hb = (flat >> 3) & 7;
    const int t = flat >> 6;
    const int tid = threadIdx.x;
    const int lane = tid & 63, wid = tid >> 6;     // 4 waves
    const int lane31 = lane & 31, tau = lane >> 5;
    const int hbase = hb * 8;

    for (int i = tid; i < XSH_ / 8; i += 256)
        *(int4*)&xs[i * 8] = (int4){0, 0, 0, 0};
    if (tid < 128) bnred[tid] = 0.f;

    const unsigned short* xnb = xb + (size_t)n * 4194304;     // [c8][t][h][w][8]
    const unsigned short* wnb = wtb2 + (size_t)n * 114688;    // [c8][28][64][8]

    f32x16 acc[2][4];
#pragma unroll
    for (int ci = 0; ci < 2; ++ci)
#pragma unroll
        for (int s = 0; s < 4; ++s)
            acc[ci][s] = (f32x16)(0.f);

    const int aBase = tau * 512 + lane31 * 8;
    int bsp[4];
#pragma unroll
    for (int s = 0; s < 4; ++s)
        bsp[s] = (2 * wid + (s >> 1)) * HS8_ + (1 + (s & 1) * 32 + lane31) * CS8_;

    for (int c8 = 0; c8 < 8; ++c8) {
        __syncthreads();   // waves done reading previous chunk (also after zero-fill)
#pragma unroll
        for (int k = 0; k < 7; ++k) {
            int tp = wid + (k << 2);
            const unsigned short* gp = wnb + ((size_t)c8 * 14336 + tp * 512 + lane * 8);
            const unsigned short* lp = &wl[tp * 512];
            __builtin_amdgcn_global_load_lds(
                (const __attribute__((address_space(1))) void*)gp,
                (__attribute__((address_space(3))) void*)lp, 16, 0, 0);
        }
#pragma unroll
        for (int k = 0; k < 8; ++k) {
            int r = wid + (k << 2);
            if (r < 30) {
                int tp = (r >= 20) ? 2 : (r >= 10 ? 1 : 0);
                int hp = r - tp * 10;
                int gt = t + tp - 1, gh = hbase + hp - 1;
                if (((unsigned)gt < 16u) && ((unsigned)gh < 64u)) {
                    const unsigned short* gp = xnb + (size_t)(((c8 * 16 + gt) * 64 + gh) * 64 + lane) * 8;
                    const unsigned short* lp = &xs[tp * TS8_ + hp * HS8_ + CS8_];
                    __builtin_amdgcn_global_load_lds(
                        (const __attribute__((address_space(1))) void*)gp,
                        (__attribute__((address_space(3))) void*)lp, 16, 0, 0);
                }
            }
        }
        __syncthreads();   // vmcnt(0) drain -> chunk staged

#pragma unroll
        for (int p = 0; p < 14; ++p) {
            const int xo = tau ? OXc(2 * p + 1) : OXc(2 * p);
            bf16x8 a0 = *(const bf16x8*)&wl[p * 1024 + aBase];
            bf16x8 a1 = *(const bf16x8*)&wl[p * 1024 + aBase + 256];
            bf16x8 b0 = *(const bf16x8*)&xs[bsp[0] + xo];
            bf16x8 b1 = *(const bf16x8*)&xs[bsp[1] + xo];
            bf16x8 b2 = *(const bf16x8*)&xs[bsp[2] + xo];
            bf16x8 b3 = *(const bf16x8*)&xs[bsp[3] + xo];
            acc[0][0] = __builtin_amdgcn_mfma_f32_32x32x16_bf16(a0, b0, acc[0][0], 0, 0, 0);
            acc[0][1] = __builtin_amdgcn_mfma_f32_32x32x16_bf16(a0, b1, acc[0][1], 0, 0, 0);
            acc[0][2] = __builtin_amdgcn_mfma_f32_32x32x16_bf16(a0, b2, acc[0][2], 0, 0, 0);
            acc[0][3] = __builtin_amdgcn_mfma_f32_32x32x16_bf16(a0, b3, acc[0][3], 0, 0, 0);
            acc[1][0] = __builtin_amdgcn_mfma_f32_32x32x16_bf16(a1, b0, acc[1][0], 0, 0, 0);
            acc[1][1] = __builtin_amdgcn_mfma_f32_32x32x16_bf16(a1, b1, acc[1][1], 0, 0, 0);
            acc[1][2] = __builtin_amdgcn_mfma_f32_32x32x16_bf16(a1, b2, acc[1][2], 0, 0, 0);
            acc[1][3] = __builtin_amdgcn_mfma_f32_32x32x16_bf16(a1, b3, acc[1][3], 0, 0, 0);
        }
    }

    // ---- epilogue: C/D col=lane31(w), row=(r&3)+8*(r>>2)+4*tau (+32*ci)
    const float* db = dynb + n * DIMS_;
    const bool bf = (ybf != nullptr);
#pragma unroll
    for (int ci = 0; ci < 2; ++ci) {
#pragma unroll
        for (int r = 0; r < 16; ++r) {
            const int co = 32 * ci + (r & 3) + 8 * (r >> 2) + 4 * tau;
            const float bco = db[co];
            float ps = 0.f, ps2 = 0.f;
#pragma unroll
            for (int s = 0; s < 4; ++s) {
                float z = acc[ci][s][r] + bco;
                size_t yi = ((size_t)(n * 64 + co) << 16) + ((size_t)t << 12)
                          + ((size_t)(hbase + 2 * wid + (s >> 1)) << 6) + (s & 1) * 32 + lane31;
                if (bf) ybf[yi] = f2bf(z);
                else    y[yi] = z;
                ps += z;
                ps2 += z * z;
            }
#pragma unroll
            for (int m = 1; m < 32; m <<= 1) {
                ps += __shfl_xor(ps, m, 64);
                ps2 += __shfl_xor(ps2, m, 64);
            }
            if (lane31 == 0) {
                atomicAdd(&bnred[co], ps);
                atomicAdd(&bnred[64 + co], ps2);
            }
        }
    }
    __syncthreads();
    if (tid < 128) atomicAdd(&sums[tid], bnred[tid]);
}

// ---------------------------------------------------------------------------
// 9a) BN normalize + relu from bf16 y -> fp32 out (fast path, non-temporal)
__global__ void bn_norm_bf(const float* __restrict__ sums, const float* __restrict__ gamma,
                           const float* __restrict__ beta,
                           const unsigned short* __restrict__ ybf, float* __restrict__ out) {
    const float cnt = (float)(N_ * THW_);
    for (size_t i8 = (size_t)blockIdx.x * 256 + threadIdx.x; i8 < 4194304;
         i8 += (size_t)4096 * 256) {
        int c = (int)((i8 >> 13) & 63);
        float mean = sums[c] / cnt;
        float var = sums[64 + c] / cnt - mean * mean;
        float sc = gamma[c] * rsqrtf(var + 1e-5f);
        float sh = beta[c] - mean * sc;
        i32x4v raw = __builtin_nontemporal_load((const i32x4v*)ybf + i8);
        const unsigned short* u = (const unsigned short*)&raw;
        f32x4v o0, o1;
        o0.x = fmaxf(fmaf(bf2f(u[0]), sc, sh), 0.f);
        o0.y = fmaxf(fmaf(bf2f(u[1]), sc, sh), 0.f);
        o0.z = fmaxf(fmaf(bf2f(u[2]), sc, sh), 0.f);
        o0.w = fmaxf(fmaf(bf2f(u[3]), sc, sh), 0.f);
        o1.x = fmaxf(fmaf(bf2f(u[4]), sc, sh), 0.f);
        o1.y = fmaxf(fmaf(bf2f(u[5]), sc, sh), 0.f);
        o1.z = fmaxf(fmaf(bf2f(u[6]), sc, sh), 0.f);
        o1.w = fmaxf(fmaf(bf2f(u[7]), sc, sh), 0.f);
        __builtin_nontemporal_store(o0, (f32x4v*)out + i8 * 2);
        __builtin_nontemporal_store(o1, (f32x4v*)out + i8 * 2 + 1);
    }
}

// 9b) BN normalize + relu, fp32 in place (fallback)
__global__ void bn_norm4(const float* __restrict__ sums, const float* __restrict__ gamma,
                         const float* __restrict__ beta, float* __restrict__ y) {
    const float cnt = (float)(N_ * THW_);
    for (size_t idx = (size_t)blockIdx.x * 256 + threadIdx.x; idx < 8388608;
         idx += (size_t)4096 * 256) {
        int c = (int)((idx >> 14) & 63);
        float mean = sums[c] / cnt;
        float var = sums[64 + c] / cnt - mean * mean;
        float sc = gamma[c] * rsqrtf(var + 1e-5f);
        float sh = beta[c] - mean * sc;
        float4 v = ((float4*)y)[idx];
        v.x = fmaxf(fmaf(v.x, sc, sh), 0.f);
        v.y = fmaxf(fmaf(v.y, sc, sh), 0.f);
        v.z = fmaxf(fmaf(v.z, sc, sh), 0.f);
        v.w = fmaxf(fmaf(v.w, sc, sh), 0.f);
        ((float4*)y)[idx] = v;
    }
}

// ---------------------------------------------------------------------------
extern "C" void kernel_launch(void* const* d_in, const int* in_sizes, int n_in,
                              void* d_out, int out_size, void* d_ws, size_t ws_size,
                              hipStream_t stream) {
    const float* x       = (const float*)d_in[0];
    const float* weights = (const float*)d_in[1];
    const float* biases  = (const float*)d_in[2];
    const float* se_w1   = (const float*)d_in[3];
    const float* se_b1   = (const float*)d_in[4];
    const float* se_w2   = (const float*)d_in[5];
    const float* se_b2   = (const float*)d_in[6];
    const float* lin_w   = (const float*)d_in[7];
    const float* lin_b   = (const float*)d_in[8];
    const float* gamma   = (const float*)d_in[9];
    const float* beta    = (const float*)d_in[10];
    const int*   epochs  = (const int*)d_in[11];

    float* out = (float*)d_out;
    float* ws = (float*)d_ws;

    // workspace layout (float slots)
    const size_t STD_OFF  = 0;                        // 2,097,152
    const size_t H1_OFF   = STD_OFF + 2097152;        // 460,800
    const size_t SUMS_OFF = H1_OFF + 460800;          // 128
    const size_t POOL_OFF = SUMS_OFF + 128;           // 256
    const size_t PHI_OFF  = POOL_OFF + 256;           // 64 (unused)
    const size_t DYNB_OFF = PHI_OFF + 64;             // 512
    const size_t WTB_OFF  = DYNB_OFF + 512;           // 458,752 (bf16 x 917,504)
    const size_t W1T_OFF  = WTB_OFF + 458752;         // 25,600
    const size_t W2T_OFF  = W1T_OFF + 25600;          // 12,800
    const size_t XB_OFF   = W2T_OFF + 12800;          // 16,777,216 (bf16 x 33.5M)
    const size_t YBF_OFF  = XB_OFF + 16777216;        // 16,777,216 (bf16 x 33.5M)
    const size_t NEEDED   = (YBF_OFF + 16777216) * 4;

    float* std_x  = ws + STD_OFF;
    float* h1     = ws + H1_OFF;
    float* sums   = ws + SUMS_OFF;
    float* pooled = ws + POOL_OFF;
    float* dynb   = ws + DYNB_OFF;
    unsigned short* wtb2 = (unsigned short*)(ws + WTB_OFF);
    float* w1t    = ws + W1T_OFF;
    float* w2t    = ws + W2T_OFF;
    unsigned short* xb = (unsigned short*)(ws + XB_OFF);
    unsigned short* ybf = (unsigned short*)(ws + YBF_OFF);

    const bool bf_path = (ws_size >= NEEDED);

    stdxb_kernel<<<dim3(64, 8, 8), 512, 0, stream>>>(
        x, std_x, xb, sums, (unsigned*)pooled, se_w1, se_w2, w1t, w2t);

    se_conv1c<<<dim3(57, 8, 2), 256, 0, stream>>>(std_x, w1t, se_b1, h1);
    se_conv2c<<<dim3(49, 8, 4), 256, 0, stream>>>(h1, w2t, se_b2, (unsigned*)pooled);

    dyn_w_head<<<432, 256, 0, stream>>>(weights, pooled, lin_w, lin_b, biases, epochs,
                                        wtb2, dynb);

    conv3d_mfma5<<<1024, 256, 0, stream>>>(
        xb, wtb2, dynb, out, bf_path ? ybf : nullptr, sums);

    if (bf_path)
        bn_norm_bf<<<4096, 256, 0, stream>>>(sums, gamma, beta, ybf, out);
    else
        bn_norm4<<<4096, 256, 0, stream>>>(sums, gamma, beta, out);
}

// Round 13
// 371.514 us; speedup vs baseline: 7.5179x; 1.0052x over previous
//
#include <hip/hip_runtime.h>
#include <hip/hip_bf16.h>
#include <math.h>

// Problem constants
#define N_   8
#define CIN_ 64
#define DIMS_ 64
#define NW_  8
#define T_   16
#define H_   64
#define W_   64
#define HW_  (H_ * W_)          // 4096
#define THW_ (T_ * HW_)         // 65536

typedef short bf16x8 __attribute__((ext_vector_type(8)));
typedef float f32x16 __attribute__((ext_vector_type(16)));
typedef int   i32x4v __attribute__((ext_vector_type(4)));
typedef float f32x4v __attribute__((ext_vector_type(4)));

__device__ __forceinline__ unsigned short f2bf(float f) {
    union { float f; unsigned u; } a; a.f = f;
    unsigned r = a.u + 0x7fffu + ((a.u >> 16) & 1u);   // RNE
    return (unsigned short)(r >> 16);
}
__device__ __forceinline__ float bf2f(unsigned short u) {
    union { unsigned u; float f; } a; a.u = ((unsigned)u) << 16; return a.f;
}

// conv LDS geometry (halfword units): x [3t][10h][66w][8cin], w [28tap][64co][8cin]
#define CS8_ 8
#define HS8_ (66 * CS8_)        // 528
#define TS8_ (10 * HS8_)        // 5280
#define XSH_ (3 * TS8_)         // 15840 hw = 31680 B
#define WLH_ (28 * 64 * 8)      // 14336 hw = 28672 B

__host__ __device__ constexpr int OXc(int tap) {
    int tt = tap > 26 ? 26 : tap;   // tap 27 = zero-weight pad -> any safe addr
    return (tt / 9) * TS8_ + ((tt % 9) / 3) * HS8_ + ((tt % 3) - 1) * CS8_;
}

// ---------------------------------------------------------------------------
// 1) fused: temporal std (ddof=1) + x -> xb bf16 [n][c8][t][h][w][8cin]
//    + SE weight transpose (first 75 flat blocks) + zero sums/pooled (block 0)
__global__ __launch_bounds__(512) void stdxb_kernel(
    const float* __restrict__ x, float* __restrict__ std_x,
    unsigned short* __restrict__ xb, float* __restrict__ sums,
    unsigned* __restrict__ pooled,
    const float* __restrict__ w1, const float* __restrict__ w2,
    float* __restrict__ w1t, float* __restrict__ w2t)
{
    __shared__ unsigned short xsl[16 * 64 * 8];   // [t][w][c] 16 KB
    const int h = blockIdx.x, c8 = blockIdx.y, n = blockIdx.z;
    const int tid = threadIdx.x;
    const int bf = blockIdx.x + (blockIdx.y << 6) + ((int)blockIdx.z << 9);
    if (bf == 0) {
        if (tid < 128) sums[tid] = 0.f;
        else if (tid < 384) pooled[tid - 128] = 0u;
    }
    if (bf < 75) {
        int i = bf * 512 + tid;
        if (i < 25600) {
            int k = i / 1600, c = (i / 25) % 64, tap = i % 25;
            w1t[(c * 25 + tap) * 16 + k] = w1[i];
        } else if (i < 38400) {
            int j = i - 25600;
            int o = j / 400, c = (j / 25) % 16, tap = j % 25;
            w2t[(c * 25 + tap) * 32 + o] = w2[j];
        }
    }
    const int c = tid >> 6, w = tid & 63;
    const int cin = c8 * 8 + c;
    const float* px = x + (((size_t)(n * 64 + cin)) << 16) + (h << 6) + w;
    float s = 0.f, s2 = 0.f;
#pragma unroll
    for (int t = 0; t < T_; ++t) {
        float v = px[t * HW_];
        s += v;
        s2 += v * v;
        xsl[(t << 9) + (w << 3) + c] = f2bf(v);
    }
    float var = (s2 - s * s * (1.0f / 16.0f)) * (1.0f / 15.0f);
    std_x[(((size_t)(n * 64 + cin)) << 12) + (h << 6) + w] = sqrtf(fmaxf(var, 0.f));
    __syncthreads();
    const int4* src = (const int4*)xsl;
    int4* dst = (int4*)(xb + ((size_t)((n * 8 + c8) * 16) << 12) * 8);
#pragma unroll
    for (int k = 0; k < 2; ++k) {
        int j = tid + (k << 9);
        int t = j >> 6, ww = j & 63;
        dst[((t << 6) + h) * 64 + ww] = src[j];
    }
}

// ---------------------------------------------------------------------------
// 2) SE conv1: block 256 = 64 ij x 4 c-quarters; 8 k per thread; LDS reduce
__global__ __launch_bounds__(256) void se_conv1c(const float* __restrict__ std_x,
        const float* __restrict__ w1t, const float* __restrict__ b1, float* __restrict__ h1) {
    __shared__ float red[3][64][8];
    const int n = blockIdx.y, ks = blockIdx.z * 8;
    const int iq = threadIdx.x & 63, cq = threadIdx.x >> 6;
    const int ij = blockIdx.x * 64 + iq;
    float acc[8];
#pragma unroll
    for (int q = 0; q < 8; ++q) acc[q] = 0.f;
    if (ij < 3600) {
        int i = ij / 60, j = ij - i * 60;
        const float* xn = std_x + (size_t)n * CIN_ * HW_ + i * W_ + j;
        for (int c = cq * 16; c < cq * 16 + 16; ++c) {
            const float* xc = xn + c * HW_;
            float xv[25];
#pragma unroll
            for (int u = 0; u < 5; ++u)
#pragma unroll
                for (int v = 0; v < 5; ++v) xv[u * 5 + v] = xc[u * W_ + v];
            const float* wc = w1t + c * 400 + ks;
#pragma unroll
            for (int tap = 0; tap < 25; ++tap)
#pragma unroll
                for (int q = 0; q < 8; ++q)
                    acc[q] = fmaf(xv[tap], wc[tap * 16 + q], acc[q]);
        }
    }
    if (cq > 0) {
#pragma unroll
        for (int q = 0; q < 8; ++q) red[cq - 1][iq][q] = acc[q];
    }
    __syncthreads();
    if (cq == 0 && ij < 3600) {
#pragma unroll
        for (int q = 0; q < 8; ++q) {
            float a = acc[q] + red[0][iq][q] + red[1][iq][q] + red[2][iq][q] + b1[ks + q];
            h1[((size_t)(n * 16 + ks + q)) * 3600 + ij] = fmaxf(a, 0.f);
        }
    }
}

// ---------------------------------------------------------------------------
// 3) SE conv2 + fused max-pool
__global__ __launch_bounds__(256) void se_conv2c(const float* __restrict__ h1,
        const float* __restrict__ w2t, const float* __restrict__ b2,
        unsigned* __restrict__ pooled) {
    __shared__ float red[3][64][8];
    const int n = blockIdx.y, os = blockIdx.z * 8;
    const int iq = threadIdx.x & 63, cq = threadIdx.x >> 6;
    const int ij = blockIdx.x * 64 + iq;   // exact 49*64 = 3136
    const int i = ij / 56, j = ij - i * 56;
    float acc[8];
#pragma unroll
    for (int q = 0; q < 8; ++q) acc[q] = 0.f;
    const float* xn = h1 + (size_t)n * 16 * 3600 + i * 60 + j;
    for (int c = cq * 4; c < cq * 4 + 4; ++c) {
        const float* xc = xn + c * 3600;
        float xv[25];
#pragma unroll
        for (int u = 0; u < 5; ++u)
#pragma unroll
            for (int v = 0; v < 5; ++v) xv[u * 5 + v] = xc[u * 60 + v];
        const float* wc = w2t + c * 800 + os;
#pragma unroll
        for (int tap = 0; tap < 25; ++tap)
#pragma unroll
            for (int q = 0; q < 8; ++q)
                acc[q] = fmaf(xv[tap], wc[tap * 32 + q], acc[q]);
    }
    if (cq > 0) {
#pragma unroll
        for (int q = 0; q < 8; ++q) red[cq - 1][iq][q] = acc[q];
    }
    __syncthreads();
    if (cq == 0) {
#pragma unroll
        for (int q = 0; q < 8; ++q) {
            float a = fmaxf(acc[q] + red[0][iq][q] + red[1][iq][q] + red[2][iq][q] + b2[os + q], 0.f);
#pragma unroll
            for (int m = 1; m < 64; m <<= 1) a = fmaxf(a, __shfl_xor(a, m, 64));
            if (iq == 0) atomicMax(&pooled[n * 32 + os + q], __float_as_uint(a));
        }
    }
}

// ---------------------------------------------------------------------------
// 6) dyn weights + head fused; block 0 writes dyn_b; first 64 blocks zero tap-27
__global__ __launch_bounds__(256) void dyn_w_head(
    const float* __restrict__ weights, const float* __restrict__ pooled,
    const float* __restrict__ lin_w, const float* __restrict__ lin_b,
    const float* __restrict__ biases, const int* __restrict__ epochs,
    unsigned short* __restrict__ wtb2, float* __restrict__ dyn_b) {
    __shared__ float slog[8][8];
    __shared__ float sphi[64];
    const int tid = threadIdx.x;
    const int e = epochs[0];
    const float tau = (e < 10) ? (30.0f - 2.9f * (float)e) : 1.0f;
    if (tid < 64) {
        int b = tid >> 3, m = tid & 7;
        float acc = lin_b[m];
#pragma unroll
        for (int k = 0; k < 32; ++k) acc += pooled[b * 32 + k] * lin_w[m * 32 + k];
        slog[b][m] = acc / tau;
    }
    __syncthreads();
    if (tid < 8) {
        float mx = slog[tid][0];
#pragma unroll
        for (int m = 1; m < 8; ++m) mx = fmaxf(mx, slog[tid][m]);
        float ex[8], ssum = 0.f;
#pragma unroll
        for (int m = 0; m < 8; ++m) { ex[m] = expf(slog[tid][m] - mx); ssum += ex[m]; }
        float inv = 1.0f / ssum;
#pragma unroll
        for (int m = 0; m < 8; ++m) sphi[tid * 8 + m] = ex[m] * inv;
    }
    __syncthreads();
    if (blockIdx.x < 64) {
        int b = blockIdx.x >> 3, c8 = blockIdx.x & 7;
        unsigned* dst = (unsigned*)(wtb2 + (size_t)b * 114688 + (size_t)(c8 * 28 + 27) * 512);
        dst[tid] = 0u;
    }
    if (blockIdx.x == 0) {
#pragma unroll
        for (int idx = tid; idx < 512; idx += 256) {
            int b = idx >> 6, d = idx & 63;
            float a = 0.f;
#pragma unroll
            for (int m = 0; m < 8; ++m) a += sphi[b * 8 + m] * biases[m * DIMS_ + d];
            dyn_b[idx] = a;
        }
    }
    int f = blockIdx.x * 256 + tid;   // 0..110591 = co*1728 + cin*27 + tap
    if (f >= 110592) return;
    int tap = f % 27, cin = (f / 27) & 63, co = f / 1728;
    float wv[8];
#pragma unroll
    for (int m = 0; m < 8; ++m) wv[m] = weights[(size_t)m * 110592 + f];
    size_t dbase = (size_t)(cin >> 3) * 14336 + tap * 512 + co * 8 + (cin & 7);
#pragma unroll
    for (int b = 0; b < 8; ++b) {
        float acc = 0.f;
#pragma unroll
        for (int m = 0; m < 8; ++m) acc += sphi[b * 8 + m] * wv[m];
        wtb2[(size_t)b * 114688 + dbase] = f2bf(acc);
    }
}

// ---------------------------------------------------------------------------
// 7) conv3d: r12 structure + chunk-order STAGGER (de-phase co-resident blocks
//    so block A's stage/drain overlaps block B's MFMA) + T5 setprio around the
//    MFMA cluster (pays only with role-split waves, which stagger creates).
//    XCD mapping: flat&7 = n. 256 thr = 4 waves, 2x4 outer product, fused BN.
__global__ __launch_bounds__(256, 2) void conv3d_mfma5(
    const unsigned short* __restrict__ xb,     // [8][8][16][64][64][8]
    const unsigned short* __restrict__ wtb2,   // [8][8][28][64][8]
    const float* __restrict__ dynb,            // [8][64]
    float* __restrict__ y,                     // fp32 out (fallback path)
    unsigned short* __restrict__ ybf,          // bf16 y (fast path) or nullptr
    float* __restrict__ sums)                  // [128]
{
    __shared__ __align__(16) unsigned short xs[XSH_];
    __shared__ __align__(16) unsigned short wl[WLH_];
    __shared__ float bnred[128];

    const int flat = blockIdx.x;
    const int n = flat & 7;                 // XCD = dispatch%8 -> n-per-XCD
    const int hb = (flat >> 3) & 7;
    const int t = flat >> 6;
    // de-phase likely co-resident blocks (pairing unknown -> hash two bits)
    const int stag = (((flat >> 3) ^ (flat >> 8)) & 1) * 4;
    const int tid = threadIdx.x;
    const int lane = tid & 63, wid = tid >> 6;     // 4 waves
    const int lane31 = lane & 31, tau = lane >> 5;
    const int hbase = hb * 8;

    for (int i = tid; i < XSH_ / 8; i += 256)
        *(int4*)&xs[i * 8] = (int4){0, 0, 0, 0};
    if (tid < 128) bnred[tid] = 0.f;

    const unsigned short* xnb = xb + (size_t)n * 4194304;     // [c8][t][h][w][8]
    const unsigned short* wnb = wtb2 + (size_t)n * 114688;    // [c8][28][64][8]

    f32x16 acc[2][4];
#pragma unroll
    for (int ci = 0; ci < 2; ++ci)
#pragma unroll
        for (int s = 0; s < 4; ++s)
            acc[ci][s] = (f32x16)(0.f);

    const int aBase = tau * 512 + lane31 * 8;
    int bsp[4];
#pragma unroll
    for (int s = 0; s < 4; ++s)
        bsp[s] = (2 * wid + (s >> 1)) * HS8_ + (1 + (s & 1) * 32 + lane31) * CS8_;

    for (int cc = 0; cc < 8; ++cc) {
        const int c8 = (cc + stag) & 7;        // rotated chunk order (FP reorder ok)
        __syncthreads();   // waves done reading previous chunk (also after zero-fill)
#pragma unroll
        for (int k = 0; k < 7; ++k) {
            int tp = wid + (k << 2);
            const unsigned short* gp = wnb + ((size_t)c8 * 14336 + tp * 512 + lane * 8);
            const unsigned short* lp = &wl[tp * 512];
            __builtin_amdgcn_global_load_lds(
                (const __attribute__((address_space(1))) void*)gp,
                (__attribute__((address_space(3))) void*)lp, 16, 0, 0);
        }
#pragma unroll
        for (int k = 0; k < 8; ++k) {
            int r = wid + (k << 2);
            if (r < 30) {
                int tp = (r >= 20) ? 2 : (r >= 10 ? 1 : 0);
                int hp = r - tp * 10;
                int gt = t + tp - 1, gh = hbase + hp - 1;
                if (((unsigned)gt < 16u) && ((unsigned)gh < 64u)) {
                    const unsigned short* gp = xnb + (size_t)(((c8 * 16 + gt) * 64 + gh) * 64 + lane) * 8;
                    const unsigned short* lp = &xs[tp * TS8_ + hp * HS8_ + CS8_];
                    __builtin_amdgcn_global_load_lds(
                        (const __attribute__((address_space(1))) void*)gp,
                        (__attribute__((address_space(3))) void*)lp, 16, 0, 0);
                }
            }
        }
        __syncthreads();   // vmcnt(0) drain -> chunk staged

        __builtin_amdgcn_s_setprio(1);
#pragma unroll
        for (int p = 0; p < 14; ++p) {
            const int xo = tau ? OXc(2 * p + 1) : OXc(2 * p);
            bf16x8 a0 = *(const bf16x8*)&wl[p * 1024 + aBase];
            bf16x8 a1 = *(const bf16x8*)&wl[p * 1024 + aBase + 256];
            bf16x8 b0 = *(const bf16x8*)&xs[bsp[0] + xo];
            bf16x8 b1 = *(const bf16x8*)&xs[bsp[1] + xo];
            bf16x8 b2 = *(const bf16x8*)&xs[bsp[2] + xo];
            bf16x8 b3 = *(const bf16x8*)&xs[bsp[3] + xo];
            acc[0][0] = __builtin_amdgcn_mfma_f32_32x32x16_bf16(a0, b0, acc[0][0], 0, 0, 0);
            acc[0][1] = __builtin_amdgcn_mfma_f32_32x32x16_bf16(a0, b1, acc[0][1], 0, 0, 0);
            acc[0][2] = __builtin_amdgcn_mfma_f32_32x32x16_bf16(a0, b2, acc[0][2], 0, 0, 0);
            acc[0][3] = __builtin_amdgcn_mfma_f32_32x32x16_bf16(a0, b3, acc[0][3], 0, 0, 0);
            acc[1][0] = __builtin_amdgcn_mfma_f32_32x32x16_bf16(a1, b0, acc[1][0], 0, 0, 0);
            acc[1][1] = __builtin_amdgcn_mfma_f32_32x32x16_bf16(a1, b1, acc[1][1], 0, 0, 0);
            acc[1][2] = __builtin_amdgcn_mfma_f32_32x32x16_bf16(a1, b2, acc[1][2], 0, 0, 0);
            acc[1][3] = __builtin_amdgcn_mfma_f32_32x32x16_bf16(a1, b3, acc[1][3], 0, 0, 0);
        }
        __builtin_amdgcn_s_setprio(0);
    }

    // ---- epilogue: C/D col=lane31(w), row=(r&3)+8*(r>>2)+4*tau (+32*ci)
    const float* db = dynb + n * DIMS_;
    const bool bf = (ybf != nullptr);
#pragma unroll
    for (int ci = 0; ci < 2; ++ci) {
#pragma unroll
        for (int r = 0; r < 16; ++r) {
            const int co = 32 * ci + (r & 3) + 8 * (r >> 2) + 4 * tau;
            const float bco = db[co];
            float ps = 0.f, ps2 = 0.f;
#pragma unroll
            for (int s = 0; s < 4; ++s) {
                float z = acc[ci][s][r] + bco;
                size_t yi = ((size_t)(n * 64 + co) << 16) + ((size_t)t << 12)
                          + ((size_t)(hbase + 2 * wid + (s >> 1)) << 6) + (s & 1) * 32 + lane31;
                if (bf) ybf[yi] = f2bf(z);
                else    y[yi] = z;
                ps += z;
                ps2 += z * z;
            }
#pragma unroll
            for (int m = 1; m < 32; m <<= 1) {
                ps += __shfl_xor(ps, m, 64);
                ps2 += __shfl_xor(ps2, m, 64);
            }
            if (lane31 == 0) {
                atomicAdd(&bnred[co], ps);
                atomicAdd(&bnred[64 + co], ps2);
            }
        }
    }
    __syncthreads();
    if (tid < 128) atomicAdd(&sums[tid], bnred[tid]);
}

// ---------------------------------------------------------------------------
// 9a) BN normalize + relu from bf16 y -> fp32 out (fast path, non-temporal)
__global__ void bn_norm_bf(const float* __restrict__ sums, const float* __restrict__ gamma,
                           const float* __restrict__ beta,
                           const unsigned short* __restrict__ ybf, float* __restrict__ out) {
    const float cnt = (float)(N_ * THW_);
    for (size_t i8 = (size_t)blockIdx.x * 256 + threadIdx.x; i8 < 4194304;
         i8 += (size_t)4096 * 256) {
        int c = (int)((i8 >> 13) & 63);
        float mean = sums[c] / cnt;
        float var = sums[64 + c] / cnt - mean * mean;
        float sc = gamma[c] * rsqrtf(var + 1e-5f);
        float sh = beta[c] - mean * sc;
        i32x4v raw = __builtin_nontemporal_load((const i32x4v*)ybf + i8);
        const unsigned short* u = (const unsigned short*)&raw;
        f32x4v o0, o1;
        o0.x = fmaxf(fmaf(bf2f(u[0]), sc, sh), 0.f);
        o0.y = fmaxf(fmaf(bf2f(u[1]), sc, sh), 0.f);
        o0.z = fmaxf(fmaf(bf2f(u[2]), sc, sh), 0.f);
        o0.w = fmaxf(fmaf(bf2f(u[3]), sc, sh), 0.f);
        o1.x = fmaxf(fmaf(bf2f(u[4]), sc, sh), 0.f);
        o1.y = fmaxf(fmaf(bf2f(u[5]), sc, sh), 0.f);
        o1.z = fmaxf(fmaf(bf2f(u[6]), sc, sh), 0.f);
        o1.w = fmaxf(fmaf(bf2f(u[7]), sc, sh), 0.f);
        __builtin_nontemporal_store(o0, (f32x4v*)out + i8 * 2);
        __builtin_nontemporal_store(o1, (f32x4v*)out + i8 * 2 + 1);
    }
}

// 9b) BN normalize + relu, fp32 in place (fallback)
__global__ void bn_norm4(const float* __restrict__ sums, const float* __restrict__ gamma,
                         const float* __restrict__ beta, float* __restrict__ y) {
    const float cnt = (float)(N_ * THW_);
    for (size_t idx = (size_t)blockIdx.x * 256 + threadIdx.x; idx < 8388608;
         idx += (size_t)4096 * 256) {
        int c = (int)((idx >> 14) & 63);
        float mean = sums[c] / cnt;
        float var = sums[64 + c] / cnt - mean * mean;
        float sc = gamma[c] * rsqrtf(var + 1e-5f);
        float sh = beta[c] - mean * sc;
        float4 v = ((float4*)y)[idx];
        v.x = fmaxf(fmaf(v.x, sc, sh), 0.f);
        v.y = fmaxf(fmaf(v.y, sc, sh), 0.f);
        v.z = fmaxf(fmaf(v.z, sc, sh), 0.f);
        v.w = fmaxf(fmaf(v.w, sc, sh), 0.f);
        ((float4*)y)[idx] = v;
    }
}

// ---------------------------------------------------------------------------
extern "C" void kernel_launch(void* const* d_in, const int* in_sizes, int n_in,
                              void* d_out, int out_size, void* d_ws, size_t ws_size,
                              hipStream_t stream) {
    const float* x       = (const float*)d_in[0];
    const float* weights = (const float*)d_in[1];
    const float* biases  = (const float*)d_in[2];
    const float* se_w1   = (const float*)d_in[3];
    const float* se_b1   = (const float*)d_in[4];
    const float* se_w2   = (const float*)d_in[5];
    const float* se_b2   = (const float*)d_in[6];
    const float* lin_w   = (const float*)d_in[7];
    const float* lin_b   = (const float*)d_in[8];
    const float* gamma   = (const float*)d_in[9];
    const float* beta    = (const float*)d_in[10];
    const int*   epochs  = (const int*)d_in[11];

    float* out = (float*)d_out;
    float* ws = (float*)d_ws;

    // workspace layout (float slots)
    const size_t STD_OFF  = 0;                        // 2,097,152
    const size_t H1_OFF   = STD_OFF + 2097152;        // 460,800
    const size_t SUMS_OFF = H1_OFF + 460800;          // 128
    const size_t POOL_OFF = SUMS_OFF + 128;           // 256
    const size_t PHI_OFF  = POOL_OFF + 256;           // 64 (unused)
    const size_t DYNB_OFF = PHI_OFF + 64;             // 512
    const size_t WTB_OFF  = DYNB_OFF + 512;           // 458,752 (bf16 x 917,504)
    const size_t W1T_OFF  = WTB_OFF + 458752;         // 25,600
    const size_t W2T_OFF  = W1T_OFF + 25600;          // 12,800
    const size_t XB_OFF   = W2T_OFF + 12800;          // 16,777,216 (bf16 x 33.5M)
    const size_t YBF_OFF  = XB_OFF + 16777216;        // 16,777,216 (bf16 x 33.5M)
    const size_t NEEDED   = (YBF_OFF + 16777216) * 4;

    float* std_x  = ws + STD_OFF;
    float* h1     = ws + H1_OFF;
    float* sums   = ws + SUMS_OFF;
    float* pooled = ws + POOL_OFF;
    float* dynb   = ws + DYNB_OFF;
    unsigned short* wtb2 = (unsigned short*)(ws + WTB_OFF);
    float* w1t    = ws + W1T_OFF;
    float* w2t    = ws + W2T_OFF;
    unsigned short* xb = (unsigned short*)(ws + XB_OFF);
    unsigned short* ybf = (unsigned short*)(ws + YBF_OFF);

    const bool bf_path = (ws_size >= NEEDED);

    stdxb_kernel<<<dim3(64, 8, 8), 512, 0, stream>>>(
        x, std_x, xb, sums, (unsigned*)pooled, se_w1, se_w2, w1t, w2t);

    se_conv1c<<<dim3(57, 8, 2), 256, 0, stream>>>(std_x, w1t, se_b1, h1);
    se_conv2c<<<dim3(49, 8, 4), 256, 0, stream>>>(h1, w2t, se_b2, (unsigned*)pooled);

    dyn_w_head<<<432, 256, 0, stream>>>(weights, pooled, lin_w, lin_b, biases, epochs,
                                        wtb2, dynb);

    conv3d_mfma5<<<1024, 256, 0, stream>>>(
        xb, wtb2, dynb, out, bf_path ? ybf : nullptr, sums);

    if (bf_path)
        bn_norm_bf<<<4096, 256, 0, stream>>>(sums, gamma, beta, ybf, out);
    else
        bn_norm4<<<4096, 256, 0, stream>>>(sums, gamma, beta, out);
}